// Round 2
// baseline (2626.108 us; speedup 1.0000x reference)
//
#include <hip/hip_runtime.h>

// ---------------- problem constants ----------------
constexpr int Nn = 50000;
constexpr int Ee = 800000;
constexpr int EF_STR  = 136; // 68 dw
constexpr int NIN_STR = 264; // 132 dw
constexpr int HIN_STR = 72;  // 36 dw
constexpr int NB_SCAN = (Nn + 255) / 256; // 196

typedef short s8v __attribute__((ext_vector_type(8)));
typedef float f4v __attribute__((ext_vector_type(4)));

__device__ __forceinline__ ushort f2bf(float f) {      // RNE
    uint u = __float_as_uint(f);
    uint r = (u + 0x7FFFu + ((u >> 16) & 1u)) >> 16;
    return (ushort)r;
}
__device__ __forceinline__ ushort f2bf_t(float f) {    // truncate (hot paths)
    return (ushort)(__float_as_uint(f) >> 16);
}
__device__ __forceinline__ float bf2f(ushort s) {
    return __uint_as_float(((uint)s) << 16);
}
__device__ __forceinline__ float silu_f(float x) {
    return x * __fdividef(1.0f, 1.0f + __expf(-x));
}
__device__ __forceinline__ uint pack2bf_t(float lo, float hi) {
    return __builtin_amdgcn_perm(__float_as_uint(hi), __float_as_uint(lo), 0x07060302u);
}
__device__ __forceinline__ uint pack2bf_r(float lo, float hi) {
    uint a = __float_as_uint(lo) + 0x8000u;
    uint b = __float_as_uint(hi) + 0x8000u;
    return __builtin_amdgcn_perm(b, a, 0x07060302u);
}

// raw barrier: LDS handoff only — no vmcnt drain, keeps global prefetch in flight
#define LBAR() do { asm volatile("s_waitcnt lgkmcnt(0)" ::: "memory"); \
                    __builtin_amdgcn_s_barrier(); } while (0)

// ---------------- merged weight pre-swizzle ----------------
// element = src[l*lstride + k*128 + n] (k<K else 0); dst [L,KC,t(8),lane(64),j(8)]
__device__ __forceinline__ void swz_one(const float* src, ushort* dst, int K, int lstride, int KC, int idx)
{
    int per = KC * 4096;
    int l = idx / per, r = idx % per;
    int fb = r >> 9, rem = r & 511;
    int lane = rem >> 3, jj = rem & 7;
    int kc = fb >> 3, t = fb & 7;
    int k = kc * 32 + ((lane >> 4) << 3) + jj;
    int n = t * 16 + (lane & 15);
    float v = (k < K) ? src[(size_t)l * lstride + (size_t)k * 128 + n] : 0.0f;
    dst[idx] = f2bf(v);
}
__global__ void __launch_bounds__(256) k_swz_all(
    const float* __restrict__ eW1, const float* __restrict__ eW2, const float* __restrict__ cW1,
    const float* __restrict__ nW1, const float* __restrict__ nW2,
    const float* __restrict__ inW, const float* __restrict__ outW,
    ushort* __restrict__ oT, ushort* __restrict__ oM,
    ushort* __restrict__ o2, ushort* __restrict__ o3,
    ushort* __restrict__ o4, ushort* __restrict__ o5,
    ushort* __restrict__ o6, ushort* __restrict__ o7)
{
    int gid = blockIdx.x * 256 + threadIdx.x;
    if (gid < 65536)       swz_one(eW1,         oT, 128, 33024, 4, gid);           // W1_top
    else if (gid < 131072) swz_one(eW1 + 16384, oM, 128, 33024, 4, gid - 65536);   // W1_mid
    else if (gid < 196608) swz_one(eW2, o2, 128, 16384, 4, gid - 131072);
    else if (gid < 262144) swz_one(cW1, o3, 128, 16384, 4, gid - 196608);
    else if (gid < 393216) swz_one(nW1, o4, 256, 32768, 8, gid - 262144);
    else if (gid < 458752) swz_one(nW2, o5, 128, 16384, 4, gid - 393216);
    else if (gid < 466944) swz_one(inW, o6, 64, 8192, 2, gid - 458752);
    else if (gid < 483328) swz_one(outW, o7, 128, 16384, 4, gid - 466944);
}

// ---------------- incoming-edge histogram ----------------
__global__ void __launch_bounds__(256) k_count(const int* __restrict__ eidx, int* __restrict__ ecnt)
{
    int e = blockIdx.x * 256 + threadIdx.x;
    atomicAdd(&ecnt[eidx[Ee + e]], 1);
}

// ---------------- multi-block exclusive scan (3 passes) ----------------
__global__ void __launch_bounds__(256) k_bsum(const int* __restrict__ ecnt, int* __restrict__ bsum)
{
    __shared__ int ws[4];
    int tid = threadIdx.x, lane = tid & 63, w = tid >> 6;
    int i = blockIdx.x * 256 + tid;
    int x = (i < Nn) ? ecnt[i] : 0;
    #pragma unroll
    for (int off = 1; off < 64; off <<= 1) x += __shfl_xor(x, off, 64);
    if (lane == 0) ws[w] = x;
    __syncthreads();
    if (tid == 0) bsum[blockIdx.x] = ws[0] + ws[1] + ws[2] + ws[3];
}
__global__ void __launch_bounds__(256) k_bscan(int* __restrict__ bsum)
{
    __shared__ int ws[4];
    int tid = threadIdx.x, lane = tid & 63, w = tid >> 6;
    int x = (tid < NB_SCAN) ? bsum[tid] : 0;
    int s = x;
    #pragma unroll
    for (int off = 1; off < 64; off <<= 1) {
        int t = __shfl_up(s, off, 64);
        if (lane >= off) s += t;
    }
    if (lane == 63) ws[w] = s;
    __syncthreads();
    if (tid == 0) { int a = 0; for (int k = 0; k < 4; k++) { int t = ws[k]; ws[k] = a; a += t; } }
    __syncthreads();
    int excl = ws[w] + s - x;
    if (tid < NB_SCAN) bsum[tid] = excl;
}
__global__ void __launch_bounds__(256) k_cursor(const int* __restrict__ ecnt,
                                               const int* __restrict__ boff, int* __restrict__ cursor)
{
    __shared__ int ws[4];
    int tid = threadIdx.x, lane = tid & 63, w = tid >> 6;
    int i = blockIdx.x * 256 + tid;
    int x = (i < Nn) ? ecnt[i] : 0;
    int s = x;
    #pragma unroll
    for (int off = 1; off < 64; off <<= 1) {
        int t = __shfl_up(s, off, 64);
        if (lane >= off) s += t;
    }
    if (lane == 63) ws[w] = s;
    __syncthreads();
    if (tid == 0) { int a = 0; for (int k = 0; k < 4; k++) { int t = ws[k]; ws[k] = a; a += t; } }
    __syncthreads();
    int excl = ws[w] + s - x + boff[blockIdx.x];
    if (i < Nn) cursor[i] = excl;
}

// ---------------- scatter edges into col-sorted arrays ----------------
__global__ void __launch_bounds__(256) k_scatter(
    const int* __restrict__ eidx, const float* __restrict__ edge_attr,
    int* __restrict__ cursor,
    int* __restrict__ srow, int* __restrict__ scol, float* __restrict__ sattr)
{
    int e = blockIdx.x * 256 + threadIdx.x;
    int r = eidx[e], c = eidx[Ee + e];
    int p = atomicAdd(&cursor[c], 1);
    srow[p] = r; scol[p] = c; sattr[p] = edge_attr[e];
}

// ---------------- input embedding (transposed MFMA, K=64) + coord copy ----------------
__global__ void __launch_bounds__(512, 2) k_emb(
    const float* __restrict__ h_in, const float* __restrict__ coords,
    const ushort* __restrict__ ws_, const float* __restrict__ b,
    float* __restrict__ hbuf, ushort* __restrict__ hbf, float* __restrict__ cbuf)
{
    __shared__ alignas(16) ushort s_h[64 * HIN_STR];
    const int tid = threadIdx.x;
    const int nb = blockIdx.x * 64;
    #pragma unroll
    for (int i = 0; i < 2; i++) {
        int idx = i * 512 + tid;
        int e = idx >> 4, ch = idx & 15;
        int node = nb + e;
        float4 f = make_float4(0.f, 0.f, 0.f, 0.f);
        if (node < Nn) f = *(const float4*)(h_in + (size_t)node * 64 + ch * 4);
        ushort4 u; u.x = f2bf(f.x); u.y = f2bf(f.y); u.z = f2bf(f.z); u.w = f2bf(f.w);
        *(ushort4*)(s_h + e * HIN_STR + ch * 4) = u;
    }
    if (tid < 192) {
        int n = nb + tid / 3, d = tid % 3;
        if (n < Nn) cbuf[n * 3 + d] = coords[n * 3 + d];
    }
    __syncthreads();
    const int lane = tid & 63, wave = tid >> 6;
    const int m = lane & 15, quad = lane >> 4;
    const int ws2 = wave >> 2, wt = wave & 3;
    const int rbase = ws2 * 32;
    f4v acc[2][2];
    #pragma unroll
    for (int nt = 0; nt < 2; nt++) { acc[nt][0] = (f4v){0,0,0,0}; acc[nt][1] = (f4v){0,0,0,0}; }
    const ushort* aBase = ws_ + wt * 1024 + lane * 8;
    #pragma unroll
    for (int kc = 0; kc < 2; kc++) {
        s8v a0 = *(const s8v*)(aBase + kc * 4096);
        s8v a1 = *(const s8v*)(aBase + kc * 4096 + 512);
        #pragma unroll
        for (int nt = 0; nt < 2; nt++) {
            s8v bf = *(const s8v*)(s_h + (rbase + nt * 16 + m) * HIN_STR + kc * 32 + quad * 8);
            acc[nt][0] = __builtin_amdgcn_mfma_f32_16x16x32_bf16(a0, bf, acc[nt][0], 0, 0, 0);
            acc[nt][1] = __builtin_amdgcn_mfma_f32_16x16x32_bf16(a1, bf, acc[nt][1], 0, 0, 0);
        }
    }
    #pragma unroll
    for (int nt = 0; nt < 2; nt++) {
        int node = nb + rbase + nt * 16 + m;
        if (node < Nn) {
            #pragma unroll
            for (int ct = 0; ct < 2; ct++) {
                int colb = (wt * 2 + ct) * 16 + quad * 4;
                float4 bb = *(const float4*)(b + colb);
                float v0 = acc[nt][ct][0] + bb.x;
                float v1 = acc[nt][ct][1] + bb.y;
                float v2 = acc[nt][ct][2] + bb.z;
                float v3 = acc[nt][ct][3] + bb.w;
                *(float4*)(hbuf + (size_t)node * 128 + colb) = make_float4(v0, v1, v2, v3);
                uint2 pk; pk.x = pack2bf_r(v0, v1); pk.y = pack2bf_r(v2, v3);
                *(uint2*)(hbf + (size_t)node * 128 + colb) = pk;
            }
        }
    }
}

// ---------------- per-layer U/V precompute: U = h@W1_top + b1, V = h@W1_mid ----------------
// uvb[n][0..127] = U (bf16 RNE), uvb[n][128..255] = V
__global__ void __launch_bounds__(512, 2) k_uv(
    const ushort* __restrict__ hbf,
    const ushort* __restrict__ topW, const ushort* __restrict__ midW,
    const float* __restrict__ b1, ushort* __restrict__ uvb)
{
    __shared__ alignas(16) ushort s_h[64 * EF_STR];
    const int tid = threadIdx.x;
    const int nb = blockIdx.x * 64;
    #pragma unroll
    for (int i = 0; i < 2; i++) {
        int idx = i * 512 + tid;
        int e = idx >> 4, ch = idx & 15;
        int node = nb + e;
        uint4 v = make_uint4(0, 0, 0, 0);
        if (node < Nn) v = *(const uint4*)(hbf + (size_t)node * 128 + ch * 8);
        *(uint4*)(s_h + e * EF_STR + ch * 8) = v;
    }
    __syncthreads();
    const int lane = tid & 63, wave = tid >> 6;
    const int m = lane & 15, quad = lane >> 4;
    const int ws2 = wave >> 2, wt = wave & 3;
    const int rbase = ws2 * 32;
    f4v au[2][2], av[2][2];
    #pragma unroll
    for (int ct = 0; ct < 2; ct++) {
        float4 bb = *(const float4*)(b1 + (wt * 2 + ct) * 16 + quad * 4);
        au[0][ct] = (f4v){bb.x, bb.y, bb.z, bb.w};
        au[1][ct] = au[0][ct];
        av[0][ct] = (f4v){0,0,0,0};
        av[1][ct] = (f4v){0,0,0,0};
    }
    const ushort* tBase = topW + wt * 1024 + (size_t)lane * 8;
    const ushort* mBase = midW + wt * 1024 + (size_t)lane * 8;
    #pragma unroll
    for (int kc = 0; kc < 4; kc++) {
        s8v t0 = *(const s8v*)(tBase + kc * 4096);
        s8v t1 = *(const s8v*)(tBase + kc * 4096 + 512);
        s8v m0 = *(const s8v*)(mBase + kc * 4096);
        s8v m1 = *(const s8v*)(mBase + kc * 4096 + 512);
        #pragma unroll
        for (int nt = 0; nt < 2; nt++) {
            s8v bf = *(const s8v*)(s_h + (rbase + nt * 16 + m) * EF_STR + kc * 32 + quad * 8);
            au[nt][0] = __builtin_amdgcn_mfma_f32_16x16x32_bf16(t0, bf, au[nt][0], 0, 0, 0);
            au[nt][1] = __builtin_amdgcn_mfma_f32_16x16x32_bf16(t1, bf, au[nt][1], 0, 0, 0);
            av[nt][0] = __builtin_amdgcn_mfma_f32_16x16x32_bf16(m0, bf, av[nt][0], 0, 0, 0);
            av[nt][1] = __builtin_amdgcn_mfma_f32_16x16x32_bf16(m1, bf, av[nt][1], 0, 0, 0);
        }
    }
    #pragma unroll
    for (int nt = 0; nt < 2; nt++) {
        int node = nb + rbase + nt * 16 + m;
        if (node < Nn) {
            #pragma unroll
            for (int ct = 0; ct < 2; ct++) {
                int colb = (wt * 2 + ct) * 16 + quad * 4;
                uint2 pu; pu.x = pack2bf_r(au[nt][ct][0], au[nt][ct][1]);
                          pu.y = pack2bf_r(au[nt][ct][2], au[nt][ct][3]);
                *(uint2*)(uvb + (size_t)node * 256 + colb) = pu;
                uint2 pv; pv.x = pack2bf_r(av[nt][ct][0], av[nt][ct][1]);
                          pv.y = pack2bf_r(av[nt][ct][2], av[nt][ct][3]);
                *(uint2*)(uvb + (size_t)node * 256 + 128 + colb) = pv;
            }
        }
    }
}

// ---------------- phase-1 helper: one bf16-pair of ef1 pre-activation ----------------
__device__ __forceinline__ uint uv_term(uint uw, uint vw, float dist, float attr,
                                        const float* wdp, const float* wap, int j)
{
    float2 w2d = *(const float2*)(wdp + 2 * j);
    float2 w2a = *(const float2*)(wap + 2 * j);
    float lo = __uint_as_float(uw << 16) + __uint_as_float(vw << 16)
             + dist * w2d.x + attr * w2a.x;
    float hi = __uint_as_float(uw & 0xFFFF0000u) + __uint_as_float(vw & 0xFFFF0000u)
             + dist * w2d.y + attr * w2a.y;
    return pack2bf_t(silu_f(lo), silu_f(hi));
}

// ---------------- fused edge kernel: persistent-block tile pipeline ----------------
// Each block grid-strides over 64-edge tiles. Scattered uvb/cbuf/meta loads for
// tile t+1 are issued during tile t's compute and stay IN FLIGHT across the raw
// barriers (lgkmcnt-only drain; no vmcnt(0)). 3 barriers per tile, no B0.
// LDS = 37888 B -> 4 blocks/CU.
__global__ void __launch_bounds__(512, 6) k_edge(
    const float* __restrict__ cbuf,
    const int* __restrict__ srow, const int* __restrict__ scol, const float* __restrict__ sattr,
    const ushort* __restrict__ uvb,
    const float* __restrict__ wd, const float* __restrict__ wa,
    const ushort* __restrict__ w2s, const float* __restrict__ b2,
    const ushort* __restrict__ cw1s, const float* __restrict__ cb1,
    const float* __restrict__ cwc,
    float* __restrict__ agg_feat, float* __restrict__ agg_coord)
{
    __shared__ alignas(16) ushort s_a[64 * EF_STR];   // ef1
    __shared__ alignas(16) ushort s_b[64 * EF_STR];   // efb
    __shared__ alignas(16) float  s_t[64 * 4];        // coord partials (4 wt slots)
    __shared__ int   s_col[2][64];                    // double-buffered meta
    __shared__ float s_cd[2][64 * 3];

    const int tid = threadIdx.x;
    const int e = tid >> 3, ch = tid & 7;
    const int lane = tid & 63, wave = tid >> 6;
    const int m = lane & 15, quad = lane >> 4;
    const int ws2 = wave >> 2, wt = wave & 3;
    const int rbase = ws2 * 32;
    constexpr int NT = Ee / 64;

    int t = blockIdx.x;
    // ---- prefetch tile 0 (meta + gathers) ----
    int eb = t * 64;
    int myrow = srow[eb + e], mycol = scol[eb + e];
    float attr = sattr[eb + e];
    float cr0 = cbuf[myrow * 3 + 0], cr1 = cbuf[myrow * 3 + 1], cr2 = cbuf[myrow * 3 + 2];
    float cc0 = cbuf[mycol * 3 + 0], cc1 = cbuf[mycol * 3 + 1], cc2 = cbuf[mycol * 3 + 2];
    uint4 ua, ub, va, vb;
    {
        const ushort* up = uvb + (size_t)mycol * 256 + ch * 16;
        const ushort* vp = uvb + (size_t)myrow * 256 + 128 + ch * 16;
        ua = *(const uint4*)up;
        ub = *(const uint4*)(up + 8);
        va = *(const uint4*)vp;
        vb = *(const uint4*)(vp + 8);
    }

    int buf = 0;
    for (; t < NT; t += gridDim.x, buf ^= 1) {
        // ---- phase 1: ef1 gather-add (uses prefetched registers) ----
        {
            float d0 = cr0 - cc0, d1 = cr1 - cc1, d2 = cr2 - cc2;
            float dist = d0 * d0 + d1 * d1 + d2 * d2;
            if (ch == 0) {
                s_col[buf][e] = mycol;
                s_cd[buf][e * 3 + 0] = d0; s_cd[buf][e * 3 + 1] = d1; s_cd[buf][e * 3 + 2] = d2;
            }
            const float* wdp = wd + ch * 16;
            const float* wap = wa + ch * 16;
            uint4 q0, q1;
            q0.x = uv_term(ua.x, va.x, dist, attr, wdp, wap, 0);
            q0.y = uv_term(ua.y, va.y, dist, attr, wdp, wap, 1);
            q0.z = uv_term(ua.z, va.z, dist, attr, wdp, wap, 2);
            q0.w = uv_term(ua.w, va.w, dist, attr, wdp, wap, 3);
            *(uint4*)(s_a + e * EF_STR + ch * 16) = q0;
            q1.x = uv_term(ub.x, vb.x, dist, attr, wdp, wap, 4);
            q1.y = uv_term(ub.y, vb.y, dist, attr, wdp, wap, 5);
            q1.z = uv_term(ub.z, vb.z, dist, attr, wdp, wap, 6);
            q1.w = uv_term(ub.w, vb.w, dist, attr, wdp, wap, 7);
            *(uint4*)(s_a + e * EF_STR + ch * 16 + 8) = q1;
        }
        // ---- prefetch tile t+stride (issued here, consumed next iteration;
        //      stays in flight across the raw barriers below) ----
        {
            int nxt = t + gridDim.x;
            int nt2 = (nxt < NT) ? nxt : t;   // clamp at tail (values unused)
            int neb = nt2 * 64;
            int nrow = srow[neb + e], ncol = scol[neb + e];
            float nattr = sattr[neb + e];
            cr0 = cbuf[nrow * 3 + 0]; cr1 = cbuf[nrow * 3 + 1]; cr2 = cbuf[nrow * 3 + 2];
            cc0 = cbuf[ncol * 3 + 0]; cc1 = cbuf[ncol * 3 + 1]; cc2 = cbuf[ncol * 3 + 2];
            const ushort* up = uvb + (size_t)ncol * 256 + ch * 16;
            const ushort* vp = uvb + (size_t)nrow * 256 + 128 + ch * 16;
            ua = *(const uint4*)up;
            ub = *(const uint4*)(up + 8);
            va = *(const uint4*)vp;
            vb = *(const uint4*)(vp + 8);
            myrow = nrow; mycol = ncol; attr = nattr;
        }
        LBAR(); // B1: ef1 ready (lgkm only — prefetch stays outstanding)

        // ---- GEMM2 (swapped operands): D[outch][edge]; epilogue -> s_b ----
        {
            f4v acc2[2][2];  // [mt][tt]
            #pragma unroll
            for (int tt = 0; tt < 2; tt++) {
                float4 bb = *(const float4*)(b2 + (wt * 2 + tt) * 16 + quad * 4);
                acc2[0][tt] = (f4v){bb.x, bb.y, bb.z, bb.w};
                acc2[1][tt] = acc2[0][tt];
            }
            const ushort* bBase = w2s + wt * 1024 + (size_t)lane * 8;
            #pragma unroll
            for (int kc = 0; kc < 4; kc++) {
                s8v b0 = *(const s8v*)(bBase + kc * 4096);
                s8v b1v = *(const s8v*)(bBase + kc * 4096 + 512);
                #pragma unroll
                for (int mt = 0; mt < 2; mt++) {
                    s8v a = *(const s8v*)(s_a + (rbase + mt * 16 + m) * EF_STR + kc * 32 + quad * 8);
                    acc2[mt][0] = __builtin_amdgcn_mfma_f32_16x16x32_bf16(b0, a, acc2[mt][0], 0, 0, 0);
                    acc2[mt][1] = __builtin_amdgcn_mfma_f32_16x16x32_bf16(b1v, a, acc2[mt][1], 0, 0, 0);
                }
            }
            #pragma unroll
            for (int mt = 0; mt < 2; mt++)
                #pragma unroll
                for (int tt = 0; tt < 2; tt++) {
                    uint2 pk;
                    pk.x = pack2bf_t(silu_f(acc2[mt][tt][0]), silu_f(acc2[mt][tt][1]));
                    pk.y = pack2bf_t(silu_f(acc2[mt][tt][2]), silu_f(acc2[mt][tt][3]));
                    *(uint2*)(s_b + (rbase + mt * 16 + m) * EF_STR + (wt * 2 + tt) * 16 + quad * 4) = pk;
                }
        }
        LBAR(); // B2: efb ready

        // ---- coord gate (swapped operands): in-lane weighted sum ----
        {
            f4v acc3[2][2];
            #pragma unroll
            for (int tt = 0; tt < 2; tt++) {
                float4 bb = *(const float4*)(cb1 + (wt * 2 + tt) * 16 + quad * 4);
                acc3[0][tt] = (f4v){bb.x, bb.y, bb.z, bb.w};
                acc3[1][tt] = acc3[0][tt];
            }
            const ushort* bBase = cw1s + wt * 1024 + (size_t)lane * 8;
            #pragma unroll
            for (int kc = 0; kc < 4; kc++) {
                s8v b0 = *(const s8v*)(bBase + kc * 4096);
                s8v b1v = *(const s8v*)(bBase + kc * 4096 + 512);
                #pragma unroll
                for (int mt = 0; mt < 2; mt++) {
                    s8v a = *(const s8v*)(s_b + (rbase + mt * 16 + m) * EF_STR + kc * 32 + quad * 8);
                    acc3[mt][0] = __builtin_amdgcn_mfma_f32_16x16x32_bf16(b0, a, acc3[mt][0], 0, 0, 0);
                    acc3[mt][1] = __builtin_amdgcn_mfma_f32_16x16x32_bf16(b1v, a, acc3[mt][1], 0, 0, 0);
                }
            }
            float p0 = 0.0f, p1 = 0.0f;
            #pragma unroll
            for (int tt = 0; tt < 2; tt++) {
                float4 wc = *(const float4*)(cwc + (wt * 2 + tt) * 16 + quad * 4);
                p0 += silu_f(acc3[0][tt][0]) * wc.x + silu_f(acc3[0][tt][1]) * wc.y
                    + silu_f(acc3[0][tt][2]) * wc.z + silu_f(acc3[0][tt][3]) * wc.w;
                p1 += silu_f(acc3[1][tt][0]) * wc.x + silu_f(acc3[1][tt][1]) * wc.y
                    + silu_f(acc3[1][tt][2]) * wc.z + silu_f(acc3[1][tt][3]) * wc.w;
            }
            p0 += __shfl_xor(p0, 16, 64);
            p0 += __shfl_xor(p0, 32, 64);
            p1 += __shfl_xor(p1, 16, 64);
            p1 += __shfl_xor(p1, 32, 64);
            if (quad == 0) {
                s_t[(rbase + m) * 4 + wt] = p0;
                s_t[(rbase + 16 + m) * 4 + wt] = p1;
            }
        }
        LBAR(); // B3: partials ready

        if (tid < 64) {
            float4 pt = *(const float4*)(s_t + tid * 4);
            float cw = pt.x + pt.y + pt.z + pt.w;
            int cn = s_col[buf][tid];
            unsafeAtomicAdd(&agg_coord[cn * 3 + 0], s_cd[buf][tid * 3 + 0] * cw);
            unsafeAtomicAdd(&agg_coord[cn * 3 + 1], s_cd[buf][tid * 3 + 1] * cw);
            unsafeAtomicAdd(&agg_coord[cn * 3 + 2], s_cd[buf][tid * 3 + 2] * cw);
        }
        // feature aggregation: 4 segments x 16 edges, run-length reduced
        {
            int j = tid & 127;
            int e0 = (tid >> 7) * 16;
            float accv = 0.0f; int cur = s_col[buf][e0];
            #pragma unroll 4
            for (int ee = e0; ee < e0 + 16; ee++) {
                int c = s_col[buf][ee];
                if (c != cur) {
                    unsafeAtomicAdd(&agg_feat[(size_t)cur * 128 + j], accv);
                    accv = 0.0f; cur = c;
                }
                accv += bf2f(s_b[ee * EF_STR + j]);
            }
            unsafeAtomicAdd(&agg_feat[(size_t)cur * 128 + j], accv);
        }
        // next iteration's phase-1 s_a writes are ordered after B3 for every
        // wave; s_b of this tile is only read before each wave's own B1(t+1).
    }
}

// ---------------- node update (transposed MFMA) + agg re-zero for next layer ----------------
__global__ void __launch_bounds__(512, 6) k_node(
    float* __restrict__ hbuf, ushort* __restrict__ hbf, float* __restrict__ cbuf,
    float* __restrict__ agg_feat, float* __restrict__ agg_coord,
    const int* __restrict__ ecnt,
    const ushort* __restrict__ w1s, const float* __restrict__ b1,
    const ushort* __restrict__ w2s, const float* __restrict__ b2)
{
    __shared__ alignas(16) ushort s_nin[64 * NIN_STR];
    __shared__ alignas(16) ushort s_t1[64 * EF_STR];
    const int tid = threadIdx.x;
    const int nb = blockIdx.x * 64;

    #pragma unroll
    for (int i = 0; i < 2; i++) {
        int idx = i * 512 + tid;
        int e = idx >> 4, ch = idx & 15;
        int node = nb + e;
        uint4 v = make_uint4(0, 0, 0, 0);
        if (node < Nn) v = *(const uint4*)(hbf + (size_t)node * 128 + ch * 8);
        *(uint4*)(s_nin + e * NIN_STR + ch * 8) = v;
    }
    #pragma unroll
    for (int i = 0; i < 4; i++) {
        int idx = i * 512 + tid;
        int e = idx >> 5, ch = idx & 31;
        int node = nb + e;
        float4 f = make_float4(0.f, 0.f, 0.f, 0.f);
        if (node < Nn) {
            f = *(const float4*)(agg_feat + (size_t)node * 128 + ch * 4);
            *(float4*)(agg_feat + (size_t)node * 128 + ch * 4) = make_float4(0.f, 0.f, 0.f, 0.f);
        }
        uint2 pk; pk.x = pack2bf_t(f.x, f.y); pk.y = pack2bf_t(f.z, f.w);
        *(uint2*)(s_nin + e * NIN_STR + 128 + ch * 4) = pk;
    }
    if (tid < 64) {
        int n = nb + tid;
        if (n < Nn) {
            float c = (float)ecnt[n]; c = (c < 1.0f) ? 1.0f : c;
            float inv = __fdividef(1.0f, c);
            cbuf[n * 3 + 0] += agg_coord[n * 3 + 0] * inv;
            cbuf[n * 3 + 1] += agg_coord[n * 3 + 1] * inv;
            cbuf[n * 3 + 2] += agg_coord[n * 3 + 2] * inv;
            agg_coord[n * 3 + 0] = 0.f; agg_coord[n * 3 + 1] = 0.f; agg_coord[n * 3 + 2] = 0.f;
        }
    }
    __syncthreads();

    const int lane = tid & 63, wave = tid >> 6;
    const int m = lane & 15, quad = lane >> 4;
    const int ws2 = wave >> 2, wt = wave & 3;
    const int rbase = ws2 * 32;

    // GEMM1^T: K=256
    {
        f4v acc[2][2];
        #pragma unroll
        for (int ct = 0; ct < 2; ct++) {
            float4 bb = *(const float4*)(b1 + (wt * 2 + ct) * 16 + quad * 4);
            acc[0][ct] = (f4v){bb.x, bb.y, bb.z, bb.w};
            acc[1][ct] = acc[0][ct];
        }
        const ushort* aBase = w1s + wt * 1024 + (size_t)lane * 8;
        #pragma unroll
        for (int kc = 0; kc < 8; kc++) {
            s8v a0 = *(const s8v*)(aBase + kc * 4096);
            s8v a1 = *(const s8v*)(aBase + kc * 4096 + 512);
            #pragma unroll
            for (int nt = 0; nt < 2; nt++) {
                s8v bf = *(const s8v*)(s_nin + (rbase + nt * 16 + m) * NIN_STR + kc * 32 + quad * 8);
                acc[nt][0] = __builtin_amdgcn_mfma_f32_16x16x32_bf16(a0, bf, acc[nt][0], 0, 0, 0);
                acc[nt][1] = __builtin_amdgcn_mfma_f32_16x16x32_bf16(a1, bf, acc[nt][1], 0, 0, 0);
            }
        }
        #pragma unroll
        for (int nt = 0; nt < 2; nt++) {
            int row = rbase + nt * 16 + m;
            #pragma unroll
            for (int ct = 0; ct < 2; ct++) {
                int colb = (wt * 2 + ct) * 16 + quad * 4;
                float v0 = silu_f(acc[nt][ct][0]);
                float v1 = silu_f(acc[nt][ct][1]);
                float v2 = silu_f(acc[nt][ct][2]);
                float v3 = silu_f(acc[nt][ct][3]);
                uint2 pk; pk.x = pack2bf_t(v0, v1); pk.y = pack2bf_t(v2, v3);
                *(uint2*)(s_t1 + row * EF_STR + colb) = pk;
            }
        }
    }
    __syncthreads();

    // GEMM2^T: K=128, residual epilogue
    {
        f4v acc[2][2];
        #pragma unroll
        for (int ct = 0; ct < 2; ct++) {
            float4 bb = *(const float4*)(b2 + (wt * 2 + ct) * 16 + quad * 4);
            acc[0][ct] = (f4v){bb.x, bb.y, bb.z, bb.w};
            acc[1][ct] = acc[0][ct];
        }
        const ushort* aBase = w2s + wt * 1024 + (size_t)lane * 8;
        #pragma unroll
        for (int kc = 0; kc < 4; kc++) {
            s8v a0 = *(const s8v*)(aBase + kc * 4096);
            s8v a1 = *(const s8v*)(aBase + kc * 4096 + 512);
            #pragma unroll
            for (int nt = 0; nt < 2; nt++) {
                s8v bf = *(const s8v*)(s_t1 + (rbase + nt * 16 + m) * EF_STR + kc * 32 + quad * 8);
                acc[nt][0] = __builtin_amdgcn_mfma_f32_16x16x32_bf16(a0, bf, acc[nt][0], 0, 0, 0);
                acc[nt][1] = __builtin_amdgcn_mfma_f32_16x16x32_bf16(a1, bf, acc[nt][1], 0, 0, 0);
            }
        }
        #pragma unroll
        for (int nt = 0; nt < 2; nt++) {
            int node = nb + rbase + nt * 16 + m;
            if (node < Nn) {
                #pragma unroll
                for (int ct = 0; ct < 2; ct++) {
                    int colb = (wt * 2 + ct) * 16 + quad * 4;
                    float4 old = *(const float4*)(hbuf + (size_t)node * 128 + colb);
                    float v0 = old.x + acc[nt][ct][0];
                    float v1 = old.y + acc[nt][ct][1];
                    float v2 = old.z + acc[nt][ct][2];
                    float v3 = old.w + acc[nt][ct][3];
                    *(float4*)(hbuf + (size_t)node * 128 + colb) = make_float4(v0, v1, v2, v3);
                    uint2 pk; pk.x = pack2bf_r(v0, v1); pk.y = pack2bf_r(v2, v3);
                    *(uint2*)(hbf + (size_t)node * 128 + colb) = pk;
                }
            }
        }
    }
}

// ---------------- output embedding (transposed MFMA) + coords out ----------------
__global__ void __launch_bounds__(512, 2) k_emb_out(
    const ushort* __restrict__ hbf, const float* __restrict__ cbuf,
    const ushort* __restrict__ ws_, const float* __restrict__ b, float* __restrict__ out)
{
    __shared__ alignas(16) ushort s_h[64 * EF_STR];
    const int tid = threadIdx.x;
    const int nb = blockIdx.x * 64;
    #pragma unroll
    for (int i = 0; i < 2; i++) {
        int idx = i * 512 + tid;
        int e = idx >> 4, ch = idx & 15;
        int node = nb + e;
        uint4 v = make_uint4(0, 0, 0, 0);
        if (node < Nn) v = *(const uint4*)(hbf + (size_t)node * 128 + ch * 8);
        *(uint4*)(s_h + e * EF_STR + ch * 8) = v;
    }
    if (tid < 192) {
        int n = nb + tid / 3, d = tid % 3;
        if (n < Nn) out[(size_t)Nn * 128 + n * 3 + d] = cbuf[n * 3 + d];
    }
    __syncthreads();
    const int lane = tid & 63, wave = tid >> 6;
    const int m = lane & 15, quad = lane >> 4;
    const int ws2 = wave >> 2, wt = wave & 3;
    const int rbase = ws2 * 32;
    f4v acc[2][2];
    #pragma unroll
    for (int ct = 0; ct < 2; ct++) {
        float4 bb = *(const float4*)(b + (wt * 2 + ct) * 16 + quad * 4);
        acc[0][ct] = (f4v){bb.x, bb.y, bb.z, bb.w};
        acc[1][ct] = acc[0][ct];
    }
    const ushort* aBase = ws_ + wt * 1024 + (size_t)lane * 8;
    #pragma unroll
    for (int kc = 0; kc < 4; kc++) {
        s8v a0 = *(const s8v*)(aBase + kc * 4096);
        s8v a1 = *(const s8v*)(aBase + kc * 4096 + 512);
        #pragma unroll
        for (int nt = 0; nt < 2; nt++) {
            s8v bf = *(const s8v*)(s_h + (rbase + nt * 16 + m) * EF_STR + kc * 32 + quad * 8);
            acc[nt][0] = __builtin_amdgcn_mfma_f32_16x16x32_bf16(a0, bf, acc[nt][0], 0, 0, 0);
            acc[nt][1] = __builtin_amdgcn_mfma_f32_16x16x32_bf16(a1, bf, acc[nt][1], 0, 0, 0);
        }
    }
    #pragma unroll
    for (int nt = 0; nt < 2; nt++) {
        int node = nb + rbase + nt * 16 + m;
        if (node < Nn) {
            #pragma unroll
            for (int ct = 0; ct < 2; ct++) {
                int colb = (wt * 2 + ct) * 16 + quad * 4;
                float4 o = make_float4(acc[nt][ct][0], acc[nt][ct][1],
                                       acc[nt][ct][2], acc[nt][ct][3]);
                *(float4*)(out + (size_t)node * 128 + colb) = o;
            }
        }
    }
}

// ---------------- host launcher ----------------
extern "C" void kernel_launch(void* const* d_in, const int* in_sizes, int n_in,
                              void* d_out, int out_size, void* d_ws, size_t ws_size,
                              hipStream_t stream)
{
    const float* h_in      = (const float*)d_in[0];
    const float* coords    = (const float*)d_in[1];
    const float* edge_attr = (const float*)d_in[2];
    const float* emb_in_W  = (const float*)d_in[3];
    const float* emb_in_b  = (const float*)d_in[4];
    const float* emb_out_W = (const float*)d_in[5];
    const float* emb_out_b = (const float*)d_in[6];
    const float* eW1 = (const float*)d_in[7];
    const float* eb1 = (const float*)d_in[8];
    const float* eW2 = (const float*)d_in[9];
    const float* eb2 = (const float*)d_in[10];
    const float* cW1 = (const float*)d_in[11];
    const float* cb1 = (const float*)d_in[12];
    const float* cWc = (const float*)d_in[13];
    const float* nW1 = (const float*)d_in[14];
    const float* nb1 = (const float*)d_in[15];
    const float* nW2 = (const float*)d_in[16];
    const float* nb2 = (const float*)d_in[17];
    const int*  eidx = (const int*)d_in[18];

    size_t off = 0;
    char* base = (char*)d_ws;
    auto alloc = [&](size_t bytes) -> char* {
        char* p = base + off;
        off += (bytes + 255) & ~(size_t)255;
        return p;
    };
    float*  hbuf      = (float*)alloc((size_t)Nn * 128 * 4);
    ushort* hbf       = (ushort*)alloc((size_t)Nn * 128 * 2);
    ushort* uvb       = (ushort*)alloc((size_t)Nn * 256 * 2);
    float*  cbuf      = (float*)alloc((size_t)Nn * 3 * 4);
    int*    ecnt      = (int*)alloc((size_t)Nn * 4);
    int*    cursor    = (int*)alloc((size_t)Nn * 4);
    int*    bsum      = (int*)alloc((size_t)NB_SCAN * 4);
    int*    srow      = (int*)alloc((size_t)Ee * 4);
    int*    scol      = (int*)alloc((size_t)Ee * 4);
    float*  sattr     = (float*)alloc((size_t)Ee * 4);
    float*  agg_feat  = (float*)alloc((size_t)Nn * 128 * 4);
    float*  agg_coord = (float*)alloc((size_t)Nn * 3 * 4);
    ushort* eW1tops   = (ushort*)alloc((size_t)4 * 16384 * 2);
    ushort* eW1mids   = (ushort*)alloc((size_t)4 * 16384 * 2);
    ushort* eW2s      = (ushort*)alloc((size_t)4 * 16384 * 2);
    ushort* cW1s      = (ushort*)alloc((size_t)4 * 16384 * 2);
    ushort* nW1s      = (ushort*)alloc((size_t)4 * 32768 * 2);
    ushort* nW2s      = (ushort*)alloc((size_t)4 * 16384 * 2);
    ushort* eInWs     = (ushort*)alloc((size_t)8192 * 2);
    ushort* eOutWs    = (ushort*)alloc((size_t)16384 * 2);

    k_swz_all<<<483328 / 256, 256, 0, stream>>>(
        eW1, eW2, cW1, nW1, nW2, emb_in_W, emb_out_W,
        eW1tops, eW1mids, eW2s, cW1s, nW1s, nW2s, eInWs, eOutWs);

    hipMemsetAsync(ecnt, 0, (size_t)Nn * 4, stream);
    k_count<<<Ee / 256, 256, 0, stream>>>(eidx, ecnt);
    k_bsum<<<NB_SCAN, 256, 0, stream>>>(ecnt, bsum);
    k_bscan<<<1, 256, 0, stream>>>(bsum);
    k_cursor<<<NB_SCAN, 256, 0, stream>>>(ecnt, bsum, cursor);
    k_scatter<<<Ee / 256, 256, 0, stream>>>(eidx, edge_attr, cursor, srow, scol, sattr);
    k_emb<<<(Nn + 63) / 64, 512, 0, stream>>>(h_in, coords, eInWs, emb_in_b, hbuf, hbf, cbuf);

    hipMemsetAsync(agg_feat, 0, (size_t)Nn * 128 * 4, stream);
    hipMemsetAsync(agg_coord, 0, (size_t)Nn * 3 * 4, stream);

    for (int l = 0; l < 4; l++) {
        k_uv<<<(Nn + 63) / 64, 512, 0, stream>>>(
            hbf, eW1tops + (size_t)l * 16384, eW1mids + (size_t)l * 16384,
            eb1 + l * 128, uvb);
        k_edge<<<2048, 512, 0, stream>>>(
            cbuf, srow, scol, sattr, uvb,
            eW1 + ((size_t)l * 258 + 256) * 128,   // Wd = W1 row 256
            eW1 + ((size_t)l * 258 + 257) * 128,   // Wa = W1 row 257
            eW2s + (size_t)l * 16384, eb2 + l * 128,
            cW1s + (size_t)l * 16384, cb1 + l * 128,
            cWc + l * 128,
            agg_feat, agg_coord);
        k_node<<<(Nn + 63) / 64, 512, 0, stream>>>(
            hbuf, hbf, cbuf, agg_feat, agg_coord, ecnt,
            nW1s + (size_t)l * 32768, nb1 + l * 128,
            nW2s + (size_t)l * 16384, nb2 + l * 128);
    }
    k_emb_out<<<(Nn + 63) / 64, 512, 0, stream>>>(hbf, cbuf, eOutWs, emb_out_b, (float*)d_out);
}

// Round 3
// 2117.448 us; speedup vs baseline: 1.2402x; 1.2402x over previous
//
#include <hip/hip_runtime.h>

// ---------------- problem constants ----------------
constexpr int Nn = 50000;
constexpr int Ee = 800000;
constexpr int EF_STR  = 136; // 68 dw
constexpr int NIN_STR = 264; // 132 dw
constexpr int HIN_STR = 72;  // 36 dw
constexpr int NB_SCAN = (Nn + 255) / 256; // 196

typedef short s8v __attribute__((ext_vector_type(8)));
typedef float f4v __attribute__((ext_vector_type(4)));

__device__ __forceinline__ ushort f2bf(float f) {      // RNE
    uint u = __float_as_uint(f);
    uint r = (u + 0x7FFFu + ((u >> 16) & 1u)) >> 16;
    return (ushort)r;
}
__device__ __forceinline__ ushort f2bf_t(float f) {    // truncate (hot paths)
    return (ushort)(__float_as_uint(f) >> 16);
}
__device__ __forceinline__ float bf2f(ushort s) {
    return __uint_as_float(((uint)s) << 16);
}
__device__ __forceinline__ float silu_f(float x) {
    return x * __fdividef(1.0f, 1.0f + __expf(-x));
}
__device__ __forceinline__ uint pack2bf_t(float lo, float hi) {
    return __builtin_amdgcn_perm(__float_as_uint(hi), __float_as_uint(lo), 0x07060302u);
}
__device__ __forceinline__ uint pack2bf_r(float lo, float hi) {
    uint a = __float_as_uint(lo) + 0x8000u;
    uint b = __float_as_uint(hi) + 0x8000u;
    return __builtin_amdgcn_perm(b, a, 0x07060302u);
}

// raw barrier: LDS handoff only — no vmcnt drain, keeps global prefetch in flight
#define LBAR() do { asm volatile("s_waitcnt lgkmcnt(0)" ::: "memory"); \
                    __builtin_amdgcn_s_barrier(); } while (0)

// ---------------- merged weight pre-swizzle ----------------
// element = src[l*lstride + k*128 + n] (k<K else 0); dst [L,KC,t(8),lane(64),j(8)]
__device__ __forceinline__ void swz_one(const float* src, ushort* dst, int K, int lstride, int KC, int idx)
{
    int per = KC * 4096;
    int l = idx / per, r = idx % per;
    int fb = r >> 9, rem = r & 511;
    int lane = rem >> 3, jj = rem & 7;
    int kc = fb >> 3, t = fb & 7;
    int k = kc * 32 + ((lane >> 4) << 3) + jj;
    int n = t * 16 + (lane & 15);
    float v = (k < K) ? src[(size_t)l * lstride + (size_t)k * 128 + n] : 0.0f;
    dst[idx] = f2bf(v);
}
__global__ void __launch_bounds__(256) k_swz_all(
    const float* __restrict__ eW1, const float* __restrict__ eW2, const float* __restrict__ cW1,
    const float* __restrict__ nW1, const float* __restrict__ nW2,
    const float* __restrict__ inW, const float* __restrict__ outW,
    ushort* __restrict__ oT, ushort* __restrict__ oM,
    ushort* __restrict__ o2, ushort* __restrict__ o3,
    ushort* __restrict__ o4, ushort* __restrict__ o5,
    ushort* __restrict__ o6, ushort* __restrict__ o7)
{
    int gid = blockIdx.x * 256 + threadIdx.x;
    if (gid < 65536)       swz_one(eW1,         oT, 128, 33024, 4, gid);           // W1_top
    else if (gid < 131072) swz_one(eW1 + 16384, oM, 128, 33024, 4, gid - 65536);   // W1_mid
    else if (gid < 196608) swz_one(eW2, o2, 128, 16384, 4, gid - 131072);
    else if (gid < 262144) swz_one(cW1, o3, 128, 16384, 4, gid - 196608);
    else if (gid < 393216) swz_one(nW1, o4, 256, 32768, 8, gid - 262144);
    else if (gid < 458752) swz_one(nW2, o5, 128, 16384, 4, gid - 393216);
    else if (gid < 466944) swz_one(inW, o6, 64, 8192, 2, gid - 458752);
    else if (gid < 483328) swz_one(outW, o7, 128, 16384, 4, gid - 466944);
}

// ---------------- incoming-edge histogram ----------------
__global__ void __launch_bounds__(256) k_count(const int* __restrict__ eidx, int* __restrict__ ecnt)
{
    int e = blockIdx.x * 256 + threadIdx.x;
    atomicAdd(&ecnt[eidx[Ee + e]], 1);
}

// ---------------- multi-block exclusive scan (3 passes) ----------------
__global__ void __launch_bounds__(256) k_bsum(const int* __restrict__ ecnt, int* __restrict__ bsum)
{
    __shared__ int ws[4];
    int tid = threadIdx.x, lane = tid & 63, w = tid >> 6;
    int i = blockIdx.x * 256 + tid;
    int x = (i < Nn) ? ecnt[i] : 0;
    #pragma unroll
    for (int off = 1; off < 64; off <<= 1) x += __shfl_xor(x, off, 64);
    if (lane == 0) ws[w] = x;
    __syncthreads();
    if (tid == 0) bsum[blockIdx.x] = ws[0] + ws[1] + ws[2] + ws[3];
}
__global__ void __launch_bounds__(256) k_bscan(int* __restrict__ bsum)
{
    __shared__ int ws[4];
    int tid = threadIdx.x, lane = tid & 63, w = tid >> 6;
    int x = (tid < NB_SCAN) ? bsum[tid] : 0;
    int s = x;
    #pragma unroll
    for (int off = 1; off < 64; off <<= 1) {
        int t = __shfl_up(s, off, 64);
        if (lane >= off) s += t;
    }
    if (lane == 63) ws[w] = s;
    __syncthreads();
    if (tid == 0) { int a = 0; for (int k = 0; k < 4; k++) { int t = ws[k]; ws[k] = a; a += t; } }
    __syncthreads();
    int excl = ws[w] + s - x;
    if (tid < NB_SCAN) bsum[tid] = excl;
}
__global__ void __launch_bounds__(256) k_cursor(const int* __restrict__ ecnt,
                                               const int* __restrict__ boff, int* __restrict__ cursor)
{
    __shared__ int ws[4];
    int tid = threadIdx.x, lane = tid & 63, w = tid >> 6;
    int i = blockIdx.x * 256 + tid;
    int x = (i < Nn) ? ecnt[i] : 0;
    int s = x;
    #pragma unroll
    for (int off = 1; off < 64; off <<= 1) {
        int t = __shfl_up(s, off, 64);
        if (lane >= off) s += t;
    }
    if (lane == 63) ws[w] = s;
    __syncthreads();
    if (tid == 0) { int a = 0; for (int k = 0; k < 4; k++) { int t = ws[k]; ws[k] = a; a += t; } }
    __syncthreads();
    int excl = ws[w] + s - x + boff[blockIdx.x];
    if (i < Nn) cursor[i] = excl;
}

// ---------------- scatter edges into col-sorted arrays ----------------
__global__ void __launch_bounds__(256) k_scatter(
    const int* __restrict__ eidx, const float* __restrict__ edge_attr,
    int* __restrict__ cursor,
    int* __restrict__ srow, int* __restrict__ scol, float* __restrict__ sattr)
{
    int e = blockIdx.x * 256 + threadIdx.x;
    int r = eidx[e], c = eidx[Ee + e];
    int p = atomicAdd(&cursor[c], 1);
    srow[p] = r; scol[p] = c; sattr[p] = edge_attr[e];
}

// ---------------- input embedding (transposed MFMA, K=64) + coord copy ----------------
__global__ void __launch_bounds__(512, 2) k_emb(
    const float* __restrict__ h_in, const float* __restrict__ coords,
    const ushort* __restrict__ ws_, const float* __restrict__ b,
    float* __restrict__ hbuf, ushort* __restrict__ hbf, float* __restrict__ cbuf)
{
    __shared__ alignas(16) ushort s_h[64 * HIN_STR];
    const int tid = threadIdx.x;
    const int nb = blockIdx.x * 64;
    #pragma unroll
    for (int i = 0; i < 2; i++) {
        int idx = i * 512 + tid;
        int e = idx >> 4, ch = idx & 15;
        int node = nb + e;
        float4 f = make_float4(0.f, 0.f, 0.f, 0.f);
        if (node < Nn) f = *(const float4*)(h_in + (size_t)node * 64 + ch * 4);
        ushort4 u; u.x = f2bf(f.x); u.y = f2bf(f.y); u.z = f2bf(f.z); u.w = f2bf(f.w);
        *(ushort4*)(s_h + e * HIN_STR + ch * 4) = u;
    }
    if (tid < 192) {
        int n = nb + tid / 3, d = tid % 3;
        if (n < Nn) cbuf[n * 3 + d] = coords[n * 3 + d];
    }
    __syncthreads();
    const int lane = tid & 63, wave = tid >> 6;
    const int m = lane & 15, quad = lane >> 4;
    const int ws2 = wave >> 2, wt = wave & 3;
    const int rbase = ws2 * 32;
    f4v acc[2][2];
    #pragma unroll
    for (int nt = 0; nt < 2; nt++) { acc[nt][0] = (f4v){0,0,0,0}; acc[nt][1] = (f4v){0,0,0,0}; }
    const ushort* aBase = ws_ + wt * 1024 + lane * 8;
    #pragma unroll
    for (int kc = 0; kc < 2; kc++) {
        s8v a0 = *(const s8v*)(aBase + kc * 4096);
        s8v a1 = *(const s8v*)(aBase + kc * 4096 + 512);
        #pragma unroll
        for (int nt = 0; nt < 2; nt++) {
            s8v bf = *(const s8v*)(s_h + (rbase + nt * 16 + m) * HIN_STR + kc * 32 + quad * 8);
            acc[nt][0] = __builtin_amdgcn_mfma_f32_16x16x32_bf16(a0, bf, acc[nt][0], 0, 0, 0);
            acc[nt][1] = __builtin_amdgcn_mfma_f32_16x16x32_bf16(a1, bf, acc[nt][1], 0, 0, 0);
        }
    }
    #pragma unroll
    for (int nt = 0; nt < 2; nt++) {
        int node = nb + rbase + nt * 16 + m;
        if (node < Nn) {
            #pragma unroll
            for (int ct = 0; ct < 2; ct++) {
                int colb = (wt * 2 + ct) * 16 + quad * 4;
                float4 bb = *(const float4*)(b + colb);
                float v0 = acc[nt][ct][0] + bb.x;
                float v1 = acc[nt][ct][1] + bb.y;
                float v2 = acc[nt][ct][2] + bb.z;
                float v3 = acc[nt][ct][3] + bb.w;
                *(float4*)(hbuf + (size_t)node * 128 + colb) = make_float4(v0, v1, v2, v3);
                uint2 pk; pk.x = pack2bf_r(v0, v1); pk.y = pack2bf_r(v2, v3);
                *(uint2*)(hbf + (size_t)node * 128 + colb) = pk;
            }
        }
    }
}

// ---------------- per-layer U/V precompute: U = h@W1_top + b1, V = h@W1_mid ----------------
// uvb[n][0..127] = U (bf16 RNE), uvb[n][128..255] = V
__global__ void __launch_bounds__(512, 2) k_uv(
    const ushort* __restrict__ hbf,
    const ushort* __restrict__ topW, const ushort* __restrict__ midW,
    const float* __restrict__ b1, ushort* __restrict__ uvb)
{
    __shared__ alignas(16) ushort s_h[64 * EF_STR];
    const int tid = threadIdx.x;
    const int nb = blockIdx.x * 64;
    #pragma unroll
    for (int i = 0; i < 2; i++) {
        int idx = i * 512 + tid;
        int e = idx >> 4, ch = idx & 15;
        int node = nb + e;
        uint4 v = make_uint4(0, 0, 0, 0);
        if (node < Nn) v = *(const uint4*)(hbf + (size_t)node * 128 + ch * 8);
        *(uint4*)(s_h + e * EF_STR + ch * 8) = v;
    }
    __syncthreads();
    const int lane = tid & 63, wave = tid >> 6;
    const int m = lane & 15, quad = lane >> 4;
    const int ws2 = wave >> 2, wt = wave & 3;
    const int rbase = ws2 * 32;
    f4v au[2][2], av[2][2];
    #pragma unroll
    for (int ct = 0; ct < 2; ct++) {
        float4 bb = *(const float4*)(b1 + (wt * 2 + ct) * 16 + quad * 4);
        au[0][ct] = (f4v){bb.x, bb.y, bb.z, bb.w};
        au[1][ct] = au[0][ct];
        av[0][ct] = (f4v){0,0,0,0};
        av[1][ct] = (f4v){0,0,0,0};
    }
    const ushort* tBase = topW + wt * 1024 + (size_t)lane * 8;
    const ushort* mBase = midW + wt * 1024 + (size_t)lane * 8;
    #pragma unroll
    for (int kc = 0; kc < 4; kc++) {
        s8v t0 = *(const s8v*)(tBase + kc * 4096);
        s8v t1 = *(const s8v*)(tBase + kc * 4096 + 512);
        s8v m0 = *(const s8v*)(mBase + kc * 4096);
        s8v m1 = *(const s8v*)(mBase + kc * 4096 + 512);
        #pragma unroll
        for (int nt = 0; nt < 2; nt++) {
            s8v bf = *(const s8v*)(s_h + (rbase + nt * 16 + m) * EF_STR + kc * 32 + quad * 8);
            au[nt][0] = __builtin_amdgcn_mfma_f32_16x16x32_bf16(t0, bf, au[nt][0], 0, 0, 0);
            au[nt][1] = __builtin_amdgcn_mfma_f32_16x16x32_bf16(t1, bf, au[nt][1], 0, 0, 0);
            av[nt][0] = __builtin_amdgcn_mfma_f32_16x16x32_bf16(m0, bf, av[nt][0], 0, 0, 0);
            av[nt][1] = __builtin_amdgcn_mfma_f32_16x16x32_bf16(m1, bf, av[nt][1], 0, 0, 0);
        }
    }
    #pragma unroll
    for (int nt = 0; nt < 2; nt++) {
        int node = nb + rbase + nt * 16 + m;
        if (node < Nn) {
            #pragma unroll
            for (int ct = 0; ct < 2; ct++) {
                int colb = (wt * 2 + ct) * 16 + quad * 4;
                uint2 pu; pu.x = pack2bf_r(au[nt][ct][0], au[nt][ct][1]);
                          pu.y = pack2bf_r(au[nt][ct][2], au[nt][ct][3]);
                *(uint2*)(uvb + (size_t)node * 256 + colb) = pu;
                uint2 pv; pv.x = pack2bf_r(av[nt][ct][0], av[nt][ct][1]);
                          pv.y = pack2bf_r(av[nt][ct][2], av[nt][ct][3]);
                *(uint2*)(uvb + (size_t)node * 256 + 128 + colb) = pv;
            }
        }
    }
}

// ---------------- phase-1 helper: one bf16-pair of ef1 pre-activation ----------------
__device__ __forceinline__ uint uv_term(uint uw, uint vw, float dist, float attr,
                                        const float* wdp, const float* wap, int j)
{
    float2 w2d = *(const float2*)(wdp + 2 * j);
    float2 w2a = *(const float2*)(wap + 2 * j);
    float lo = __uint_as_float(uw << 16) + __uint_as_float(vw << 16)
             + dist * w2d.x + attr * w2a.x;
    float hi = __uint_as_float(uw & 0xFFFF0000u) + __uint_as_float(vw & 0xFFFF0000u)
             + dist * w2d.y + attr * w2a.y;
    return pack2bf_t(silu_f(lo), silu_f(hi));
}

// ---------------- fused edge kernel: 2-tile pipelined, sequential mapping ----------------
// Block b handles tiles 2b, 2b+1 (CONSECUTIVE — preserves the L2 locality of the
// col-sorted edge stream; concurrent window stays contiguous). Tile 2b+1's
// scattered uvb/cbuf/meta loads are issued during tile 2b's compute and stay in
// flight across the lgkm-only barriers (no vmcnt(0) drain). 3 barriers/tile.
// LDS = 37888 B -> 4 blocks/CU.
__global__ void __launch_bounds__(512, 6) k_edge(
    const float* __restrict__ cbuf,
    const int* __restrict__ srow, const int* __restrict__ scol, const float* __restrict__ sattr,
    const ushort* __restrict__ uvb,
    const float* __restrict__ wd, const float* __restrict__ wa,
    const ushort* __restrict__ w2s, const float* __restrict__ b2,
    const ushort* __restrict__ cw1s, const float* __restrict__ cb1,
    const float* __restrict__ cwc,
    float* __restrict__ agg_feat, float* __restrict__ agg_coord)
{
    __shared__ alignas(16) ushort s_a[64 * EF_STR];   // ef1
    __shared__ alignas(16) ushort s_b[64 * EF_STR];   // efb
    __shared__ alignas(16) float  s_t[64 * 4];        // coord partials (4 wt slots)
    __shared__ int   s_col[2][64];                    // double-buffered meta
    __shared__ float s_cd[2][64 * 3];

    const int tid = threadIdx.x;
    const int e = tid >> 3, ch = tid & 7;
    const int lane = tid & 63, wave = tid >> 6;
    const int m = lane & 15, quad = lane >> 4;
    const int ws2 = wave >> 2, wt = wave & 3;
    const int rbase = ws2 * 32;

    const int t0 = blockIdx.x * 2;
    // ---- prologue: prefetch tile t0 (meta + gathers) ----
    int eb = t0 * 64;
    int mycol = scol[eb + e];
    int myrow = srow[eb + e];
    float attr = sattr[eb + e];
    float cr0 = cbuf[myrow * 3 + 0], cr1 = cbuf[myrow * 3 + 1], cr2 = cbuf[myrow * 3 + 2];
    float cc0 = cbuf[mycol * 3 + 0], cc1 = cbuf[mycol * 3 + 1], cc2 = cbuf[mycol * 3 + 2];
    uint4 ua, ub, va, vb;
    {
        const ushort* up = uvb + (size_t)mycol * 256 + ch * 16;
        const ushort* vp = uvb + (size_t)myrow * 256 + 128 + ch * 16;
        ua = *(const uint4*)up;
        ub = *(const uint4*)(up + 8);
        va = *(const uint4*)vp;
        vb = *(const uint4*)(vp + 8);
    }

    int buf = 0;
    #pragma unroll
    for (int it = 0; it < 2; ++it, buf ^= 1) {
        int nrow = 0, ncol = 0;
        float nattr = 0.0f;
        if (it == 0) {
            // early idx prefetch for tile t0+1 — issued before the silu math so the
            // dependent uvb/cbuf gathers below don't stall on these loads
            int neb = (t0 + 1) * 64;
            nrow = srow[neb + e]; ncol = scol[neb + e]; nattr = sattr[neb + e];
        }
        // ---- phase 1: ef1 gather-add (uses prefetched registers) ----
        {
            float d0 = cr0 - cc0, d1 = cr1 - cc1, d2 = cr2 - cc2;
            float dist = d0 * d0 + d1 * d1 + d2 * d2;
            if (ch == 0) {
                s_col[buf][e] = mycol;
                s_cd[buf][e * 3 + 0] = d0; s_cd[buf][e * 3 + 1] = d1; s_cd[buf][e * 3 + 2] = d2;
            }
            const float* wdp = wd + ch * 16;
            const float* wap = wa + ch * 16;
            uint4 q0, q1;
            q0.x = uv_term(ua.x, va.x, dist, attr, wdp, wap, 0);
            q0.y = uv_term(ua.y, va.y, dist, attr, wdp, wap, 1);
            q0.z = uv_term(ua.z, va.z, dist, attr, wdp, wap, 2);
            q0.w = uv_term(ua.w, va.w, dist, attr, wdp, wap, 3);
            *(uint4*)(s_a + e * EF_STR + ch * 16) = q0;
            q1.x = uv_term(ub.x, vb.x, dist, attr, wdp, wap, 4);
            q1.y = uv_term(ub.y, vb.y, dist, attr, wdp, wap, 5);
            q1.z = uv_term(ub.z, vb.z, dist, attr, wdp, wap, 6);
            q1.w = uv_term(ub.w, vb.w, dist, attr, wdp, wap, 7);
            *(uint4*)(s_a + e * EF_STR + ch * 16 + 8) = q1;
        }
        if (it == 0) {
            // ---- issue tile t0+1 gathers: consumed next iteration, in flight
            //      across the raw barriers below ----
            cr0 = cbuf[nrow * 3 + 0]; cr1 = cbuf[nrow * 3 + 1]; cr2 = cbuf[nrow * 3 + 2];
            cc0 = cbuf[ncol * 3 + 0]; cc1 = cbuf[ncol * 3 + 1]; cc2 = cbuf[ncol * 3 + 2];
            const ushort* up = uvb + (size_t)ncol * 256 + ch * 16;
            const ushort* vp = uvb + (size_t)nrow * 256 + 128 + ch * 16;
            ua = *(const uint4*)up;
            ub = *(const uint4*)(up + 8);
            va = *(const uint4*)vp;
            vb = *(const uint4*)(vp + 8);
            myrow = nrow; mycol = ncol; attr = nattr;
        }
        LBAR(); // B1: ef1 ready (lgkm only — prefetch stays outstanding)

        // ---- GEMM2 (swapped operands): D[outch][edge]; epilogue -> s_b ----
        {
            f4v acc2[2][2];  // [mt][tt]
            #pragma unroll
            for (int tt = 0; tt < 2; tt++) {
                float4 bb = *(const float4*)(b2 + (wt * 2 + tt) * 16 + quad * 4);
                acc2[0][tt] = (f4v){bb.x, bb.y, bb.z, bb.w};
                acc2[1][tt] = acc2[0][tt];
            }
            const ushort* bBase = w2s + wt * 1024 + (size_t)lane * 8;
            #pragma unroll
            for (int kc = 0; kc < 4; kc++) {
                s8v b0 = *(const s8v*)(bBase + kc * 4096);
                s8v b1v = *(const s8v*)(bBase + kc * 4096 + 512);
                #pragma unroll
                for (int mt = 0; mt < 2; mt++) {
                    s8v a = *(const s8v*)(s_a + (rbase + mt * 16 + m) * EF_STR + kc * 32 + quad * 8);
                    acc2[mt][0] = __builtin_amdgcn_mfma_f32_16x16x32_bf16(b0, a, acc2[mt][0], 0, 0, 0);
                    acc2[mt][1] = __builtin_amdgcn_mfma_f32_16x16x32_bf16(b1v, a, acc2[mt][1], 0, 0, 0);
                }
            }
            #pragma unroll
            for (int mt = 0; mt < 2; mt++)
                #pragma unroll
                for (int tt = 0; tt < 2; tt++) {
                    uint2 pk;
                    pk.x = pack2bf_t(silu_f(acc2[mt][tt][0]), silu_f(acc2[mt][tt][1]));
                    pk.y = pack2bf_t(silu_f(acc2[mt][tt][2]), silu_f(acc2[mt][tt][3]));
                    *(uint2*)(s_b + (rbase + mt * 16 + m) * EF_STR + (wt * 2 + tt) * 16 + quad * 4) = pk;
                }
        }
        LBAR(); // B2: efb ready

        // ---- coord gate (swapped operands): in-lane weighted sum ----
        {
            f4v acc3[2][2];
            #pragma unroll
            for (int tt = 0; tt < 2; tt++) {
                float4 bb = *(const float4*)(cb1 + (wt * 2 + tt) * 16 + quad * 4);
                acc3[0][tt] = (f4v){bb.x, bb.y, bb.z, bb.w};
                acc3[1][tt] = acc3[0][tt];
            }
            const ushort* bBase = cw1s + wt * 1024 + (size_t)lane * 8;
            #pragma unroll
            for (int kc = 0; kc < 4; kc++) {
                s8v b0 = *(const s8v*)(bBase + kc * 4096);
                s8v b1v = *(const s8v*)(bBase + kc * 4096 + 512);
                #pragma unroll
                for (int mt = 0; mt < 2; mt++) {
                    s8v a = *(const s8v*)(s_b + (rbase + mt * 16 + m) * EF_STR + kc * 32 + quad * 8);
                    acc3[mt][0] = __builtin_amdgcn_mfma_f32_16x16x32_bf16(b0, a, acc3[mt][0], 0, 0, 0);
                    acc3[mt][1] = __builtin_amdgcn_mfma_f32_16x16x32_bf16(b1v, a, acc3[mt][1], 0, 0, 0);
                }
            }
            float p0 = 0.0f, p1 = 0.0f;
            #pragma unroll
            for (int tt = 0; tt < 2; tt++) {
                float4 wc = *(const float4*)(cwc + (wt * 2 + tt) * 16 + quad * 4);
                p0 += silu_f(acc3[0][tt][0]) * wc.x + silu_f(acc3[0][tt][1]) * wc.y
                    + silu_f(acc3[0][tt][2]) * wc.z + silu_f(acc3[0][tt][3]) * wc.w;
                p1 += silu_f(acc3[1][tt][0]) * wc.x + silu_f(acc3[1][tt][1]) * wc.y
                    + silu_f(acc3[1][tt][2]) * wc.z + silu_f(acc3[1][tt][3]) * wc.w;
            }
            p0 += __shfl_xor(p0, 16, 64);
            p0 += __shfl_xor(p0, 32, 64);
            p1 += __shfl_xor(p1, 16, 64);
            p1 += __shfl_xor(p1, 32, 64);
            if (quad == 0) {
                s_t[(rbase + m) * 4 + wt] = p0;
                s_t[(rbase + 16 + m) * 4 + wt] = p1;
            }
        }
        LBAR(); // B3: partials ready

        if (tid < 64) {
            float4 pt = *(const float4*)(s_t + tid * 4);
            float cw = pt.x + pt.y + pt.z + pt.w;
            int cn = s_col[buf][tid];
            unsafeAtomicAdd(&agg_coord[cn * 3 + 0], s_cd[buf][tid * 3 + 0] * cw);
            unsafeAtomicAdd(&agg_coord[cn * 3 + 1], s_cd[buf][tid * 3 + 1] * cw);
            unsafeAtomicAdd(&agg_coord[cn * 3 + 2], s_cd[buf][tid * 3 + 2] * cw);
        }
        // feature aggregation: 4 segments x 16 edges, run-length reduced
        {
            int j = tid & 127;
            int e0 = (tid >> 7) * 16;
            float accv = 0.0f; int cur = s_col[buf][e0];
            #pragma unroll 4
            for (int ee = e0; ee < e0 + 16; ee++) {
                int c = s_col[buf][ee];
                if (c != cur) {
                    unsafeAtomicAdd(&agg_feat[(size_t)cur * 128 + j], accv);
                    accv = 0.0f; cur = c;
                }
                accv += bf2f(s_b[ee * EF_STR + j]);
            }
            unsafeAtomicAdd(&agg_feat[(size_t)cur * 128 + j], accv);
        }
        // iter-1 phase-1 s_a writes are ordered after B3 (all waves passed B2's
        // s_a reads); iter-0 s_b tail-reads complete before each wave's B1(it1).
    }
}

// ---------------- node update (transposed MFMA) + agg re-zero for next layer ----------------
__global__ void __launch_bounds__(512, 6) k_node(
    float* __restrict__ hbuf, ushort* __restrict__ hbf, float* __restrict__ cbuf,
    float* __restrict__ agg_feat, float* __restrict__ agg_coord,
    const int* __restrict__ ecnt,
    const ushort* __restrict__ w1s, const float* __restrict__ b1,
    const ushort* __restrict__ w2s, const float* __restrict__ b2)
{
    __shared__ alignas(16) ushort s_nin[64 * NIN_STR];
    __shared__ alignas(16) ushort s_t1[64 * EF_STR];
    const int tid = threadIdx.x;
    const int nb = blockIdx.x * 64;

    #pragma unroll
    for (int i = 0; i < 2; i++) {
        int idx = i * 512 + tid;
        int e = idx >> 4, ch = idx & 15;
        int node = nb + e;
        uint4 v = make_uint4(0, 0, 0, 0);
        if (node < Nn) v = *(const uint4*)(hbf + (size_t)node * 128 + ch * 8);
        *(uint4*)(s_nin + e * NIN_STR + ch * 8) = v;
    }
    #pragma unroll
    for (int i = 0; i < 4; i++) {
        int idx = i * 512 + tid;
        int e = idx >> 5, ch = idx & 31;
        int node = nb + e;
        float4 f = make_float4(0.f, 0.f, 0.f, 0.f);
        if (node < Nn) {
            f = *(const float4*)(agg_feat + (size_t)node * 128 + ch * 4);
            *(float4*)(agg_feat + (size_t)node * 128 + ch * 4) = make_float4(0.f, 0.f, 0.f, 0.f);
        }
        uint2 pk; pk.x = pack2bf_t(f.x, f.y); pk.y = pack2bf_t(f.z, f.w);
        *(uint2*)(s_nin + e * NIN_STR + 128 + ch * 4) = pk;
    }
    if (tid < 64) {
        int n = nb + tid;
        if (n < Nn) {
            float c = (float)ecnt[n]; c = (c < 1.0f) ? 1.0f : c;
            float inv = __fdividef(1.0f, c);
            cbuf[n * 3 + 0] += agg_coord[n * 3 + 0] * inv;
            cbuf[n * 3 + 1] += agg_coord[n * 3 + 1] * inv;
            cbuf[n * 3 + 2] += agg_coord[n * 3 + 2] * inv;
            agg_coord[n * 3 + 0] = 0.f; agg_coord[n * 3 + 1] = 0.f; agg_coord[n * 3 + 2] = 0.f;
        }
    }
    __syncthreads();

    const int lane = tid & 63, wave = tid >> 6;
    const int m = lane & 15, quad = lane >> 4;
    const int ws2 = wave >> 2, wt = wave & 3;
    const int rbase = ws2 * 32;

    // GEMM1^T: K=256
    {
        f4v acc[2][2];
        #pragma unroll
        for (int ct = 0; ct < 2; ct++) {
            float4 bb = *(const float4*)(b1 + (wt * 2 + ct) * 16 + quad * 4);
            acc[0][ct] = (f4v){bb.x, bb.y, bb.z, bb.w};
            acc[1][ct] = acc[0][ct];
        }
        const ushort* aBase = w1s + wt * 1024 + (size_t)lane * 8;
        #pragma unroll
        for (int kc = 0; kc < 8; kc++) {
            s8v a0 = *(const s8v*)(aBase + kc * 4096);
            s8v a1 = *(const s8v*)(aBase + kc * 4096 + 512);
            #pragma unroll
            for (int nt = 0; nt < 2; nt++) {
                s8v bf = *(const s8v*)(s_nin + (rbase + nt * 16 + m) * NIN_STR + kc * 32 + quad * 8);
                acc[nt][0] = __builtin_amdgcn_mfma_f32_16x16x32_bf16(a0, bf, acc[nt][0], 0, 0, 0);
                acc[nt][1] = __builtin_amdgcn_mfma_f32_16x16x32_bf16(a1, bf, acc[nt][1], 0, 0, 0);
            }
        }
        #pragma unroll
        for (int nt = 0; nt < 2; nt++) {
            int row = rbase + nt * 16 + m;
            #pragma unroll
            for (int ct = 0; ct < 2; ct++) {
                int colb = (wt * 2 + ct) * 16 + quad * 4;
                float v0 = silu_f(acc[nt][ct][0]);
                float v1 = silu_f(acc[nt][ct][1]);
                float v2 = silu_f(acc[nt][ct][2]);
                float v3 = silu_f(acc[nt][ct][3]);
                uint2 pk; pk.x = pack2bf_t(v0, v1); pk.y = pack2bf_t(v2, v3);
                *(uint2*)(s_t1 + row * EF_STR + colb) = pk;
            }
        }
    }
    __syncthreads();

    // GEMM2^T: K=128, residual epilogue
    {
        f4v acc[2][2];
        #pragma unroll
        for (int ct = 0; ct < 2; ct++) {
            float4 bb = *(const float4*)(b2 + (wt * 2 + ct) * 16 + quad * 4);
            acc[0][ct] = (f4v){bb.x, bb.y, bb.z, bb.w};
            acc[1][ct] = acc[0][ct];
        }
        const ushort* aBase = w2s + wt * 1024 + (size_t)lane * 8;
        #pragma unroll
        for (int kc = 0; kc < 4; kc++) {
            s8v a0 = *(const s8v*)(aBase + kc * 4096);
            s8v a1 = *(const s8v*)(aBase + kc * 4096 + 512);
            #pragma unroll
            for (int nt = 0; nt < 2; nt++) {
                s8v bf = *(const s8v*)(s_t1 + (rbase + nt * 16 + m) * EF_STR + kc * 32 + quad * 8);
                acc[nt][0] = __builtin_amdgcn_mfma_f32_16x16x32_bf16(a0, bf, acc[nt][0], 0, 0, 0);
                acc[nt][1] = __builtin_amdgcn_mfma_f32_16x16x32_bf16(a1, bf, acc[nt][1], 0, 0, 0);
            }
        }
        #pragma unroll
        for (int nt = 0; nt < 2; nt++) {
            int node = nb + rbase + nt * 16 + m;
            if (node < Nn) {
                #pragma unroll
                for (int ct = 0; ct < 2; ct++) {
                    int colb = (wt * 2 + ct) * 16 + quad * 4;
                    float4 old = *(const float4*)(hbuf + (size_t)node * 128 + colb);
                    float v0 = old.x + acc[nt][ct][0];
                    float v1 = old.y + acc[nt][ct][1];
                    float v2 = old.z + acc[nt][ct][2];
                    float v3 = old.w + acc[nt][ct][3];
                    *(float4*)(hbuf + (size_t)node * 128 + colb) = make_float4(v0, v1, v2, v3);
                    uint2 pk; pk.x = pack2bf_r(v0, v1); pk.y = pack2bf_r(v2, v3);
                    *(uint2*)(hbf + (size_t)node * 128 + colb) = pk;
                }
            }
        }
    }
}

// ---------------- output embedding (transposed MFMA) + coords out ----------------
__global__ void __launch_bounds__(512, 2) k_emb_out(
    const ushort* __restrict__ hbf, const float* __restrict__ cbuf,
    const ushort* __restrict__ ws_, const float* __restrict__ b, float* __restrict__ out)
{
    __shared__ alignas(16) ushort s_h[64 * EF_STR];
    const int tid = threadIdx.x;
    const int nb = blockIdx.x * 64;
    #pragma unroll
    for (int i = 0; i < 2; i++) {
        int idx = i * 512 + tid;
        int e = idx >> 4, ch = idx & 15;
        int node = nb + e;
        uint4 v = make_uint4(0, 0, 0, 0);
        if (node < Nn) v = *(const uint4*)(hbf + (size_t)node * 128 + ch * 8);
        *(uint4*)(s_h + e * EF_STR + ch * 8) = v;
    }
    if (tid < 192) {
        int n = nb + tid / 3, d = tid % 3;
        if (n < Nn) out[(size_t)Nn * 128 + n * 3 + d] = cbuf[n * 3 + d];
    }
    __syncthreads();
    const int lane = tid & 63, wave = tid >> 6;
    const int m = lane & 15, quad = lane >> 4;
    const int ws2 = wave >> 2, wt = wave & 3;
    const int rbase = ws2 * 32;
    f4v acc[2][2];
    #pragma unroll
    for (int ct = 0; ct < 2; ct++) {
        float4 bb = *(const float4*)(b + (wt * 2 + ct) * 16 + quad * 4);
        acc[0][ct] = (f4v){bb.x, bb.y, bb.z, bb.w};
        acc[1][ct] = acc[0][ct];
    }
    const ushort* aBase = ws_ + wt * 1024 + (size_t)lane * 8;
    #pragma unroll
    for (int kc = 0; kc < 4; kc++) {
        s8v a0 = *(const s8v*)(aBase + kc * 4096);
        s8v a1 = *(const s8v*)(aBase + kc * 4096 + 512);
        #pragma unroll
        for (int nt = 0; nt < 2; nt++) {
            s8v bf = *(const s8v*)(s_h + (rbase + nt * 16 + m) * EF_STR + kc * 32 + quad * 8);
            acc[nt][0] = __builtin_amdgcn_mfma_f32_16x16x32_bf16(a0, bf, acc[nt][0], 0, 0, 0);
            acc[nt][1] = __builtin_amdgcn_mfma_f32_16x16x32_bf16(a1, bf, acc[nt][1], 0, 0, 0);
        }
    }
    #pragma unroll
    for (int nt = 0; nt < 2; nt++) {
        int node = nb + rbase + nt * 16 + m;
        if (node < Nn) {
            #pragma unroll
            for (int ct = 0; ct < 2; ct++) {
                int colb = (wt * 2 + ct) * 16 + quad * 4;
                float4 o = make_float4(acc[nt][ct][0], acc[nt][ct][1],
                                       acc[nt][ct][2], acc[nt][ct][3]);
                *(float4*)(out + (size_t)node * 128 + colb) = o;
            }
        }
    }
}

// ---------------- host launcher ----------------
extern "C" void kernel_launch(void* const* d_in, const int* in_sizes, int n_in,
                              void* d_out, int out_size, void* d_ws, size_t ws_size,
                              hipStream_t stream)
{
    const float* h_in      = (const float*)d_in[0];
    const float* coords    = (const float*)d_in[1];
    const float* edge_attr = (const float*)d_in[2];
    const float* emb_in_W  = (const float*)d_in[3];
    const float* emb_in_b  = (const float*)d_in[4];
    const float* emb_out_W = (const float*)d_in[5];
    const float* emb_out_b = (const float*)d_in[6];
    const float* eW1 = (const float*)d_in[7];
    const float* eb1 = (const float*)d_in[8];
    const float* eW2 = (const float*)d_in[9];
    const float* eb2 = (const float*)d_in[10];
    const float* cW1 = (const float*)d_in[11];
    const float* cb1 = (const float*)d_in[12];
    const float* cWc = (const float*)d_in[13];
    const float* nW1 = (const float*)d_in[14];
    const float* nb1 = (const float*)d_in[15];
    const float* nW2 = (const float*)d_in[16];
    const float* nb2 = (const float*)d_in[17];
    const int*  eidx = (const int*)d_in[18];

    size_t off = 0;
    char* base = (char*)d_ws;
    auto alloc = [&](size_t bytes) -> char* {
        char* p = base + off;
        off += (bytes + 255) & ~(size_t)255;
        return p;
    };
    float*  hbuf      = (float*)alloc((size_t)Nn * 128 * 4);
    ushort* hbf       = (ushort*)alloc((size_t)Nn * 128 * 2);
    ushort* uvb       = (ushort*)alloc((size_t)Nn * 256 * 2);
    float*  cbuf      = (float*)alloc((size_t)Nn * 3 * 4);
    int*    ecnt      = (int*)alloc((size_t)Nn * 4);
    int*    cursor    = (int*)alloc((size_t)Nn * 4);
    int*    bsum      = (int*)alloc((size_t)NB_SCAN * 4);
    int*    srow      = (int*)alloc((size_t)Ee * 4);
    int*    scol      = (int*)alloc((size_t)Ee * 4);
    float*  sattr     = (float*)alloc((size_t)Ee * 4);
    float*  agg_feat  = (float*)alloc((size_t)Nn * 128 * 4);
    float*  agg_coord = (float*)alloc((size_t)Nn * 3 * 4);
    ushort* eW1tops   = (ushort*)alloc((size_t)4 * 16384 * 2);
    ushort* eW1mids   = (ushort*)alloc((size_t)4 * 16384 * 2);
    ushort* eW2s      = (ushort*)alloc((size_t)4 * 16384 * 2);
    ushort* cW1s      = (ushort*)alloc((size_t)4 * 16384 * 2);
    ushort* nW1s      = (ushort*)alloc((size_t)4 * 32768 * 2);
    ushort* nW2s      = (ushort*)alloc((size_t)4 * 16384 * 2);
    ushort* eInWs     = (ushort*)alloc((size_t)8192 * 2);
    ushort* eOutWs    = (ushort*)alloc((size_t)16384 * 2);

    k_swz_all<<<483328 / 256, 256, 0, stream>>>(
        eW1, eW2, cW1, nW1, nW2, emb_in_W, emb_out_W,
        eW1tops, eW1mids, eW2s, cW1s, nW1s, nW2s, eInWs, eOutWs);

    hipMemsetAsync(ecnt, 0, (size_t)Nn * 4, stream);
    k_count<<<Ee / 256, 256, 0, stream>>>(eidx, ecnt);
    k_bsum<<<NB_SCAN, 256, 0, stream>>>(ecnt, bsum);
    k_bscan<<<1, 256, 0, stream>>>(bsum);
    k_cursor<<<NB_SCAN, 256, 0, stream>>>(ecnt, bsum, cursor);
    k_scatter<<<Ee / 256, 256, 0, stream>>>(eidx, edge_attr, cursor, srow, scol, sattr);
    k_emb<<<(Nn + 63) / 64, 512, 0, stream>>>(h_in, coords, eInWs, emb_in_b, hbuf, hbf, cbuf);

    hipMemsetAsync(agg_feat, 0, (size_t)Nn * 128 * 4, stream);
    hipMemsetAsync(agg_coord, 0, (size_t)Nn * 3 * 4, stream);

    for (int l = 0; l < 4; l++) {
        k_uv<<<(Nn + 63) / 64, 512, 0, stream>>>(
            hbf, eW1tops + (size_t)l * 16384, eW1mids + (size_t)l * 16384,
            eb1 + l * 128, uvb);
        k_edge<<<Ee / 128, 512, 0, stream>>>(
            cbuf, srow, scol, sattr, uvb,
            eW1 + ((size_t)l * 258 + 256) * 128,   // Wd = W1 row 256
            eW1 + ((size_t)l * 258 + 257) * 128,   // Wa = W1 row 257
            eW2s + (size_t)l * 16384, eb2 + l * 128,
            cW1s + (size_t)l * 16384, cb1 + l * 128,
            cWc + l * 128,
            agg_feat, agg_coord);
        k_node<<<(Nn + 63) / 64, 512, 0, stream>>>(
            hbuf, hbf, cbuf, agg_feat, agg_coord, ecnt,
            nW1s + (size_t)l * 32768, nb1 + l * 128,
            nW2s + (size_t)l * 16384, nb2 + l * 128);
    }
    k_emb_out<<<(Nn + 63) / 64, 512, 0, stream>>>(hbf, cbuf, eOutWs, emb_out_b, (float*)d_out);
}

// Round 4
// 1578.884 us; speedup vs baseline: 1.6633x; 1.3411x over previous
//
#include <hip/hip_runtime.h>

// ---------------- problem constants ----------------
constexpr int Nn = 50000;
constexpr int Ee = 800000;
constexpr int EF_STR  = 136; // 68 dw
constexpr int NIN_STR = 264; // 132 dw
constexpr int HIN_STR = 72;  // 36 dw
constexpr int NB_SCAN = (Nn + 255) / 256; // 196

typedef short s8v __attribute__((ext_vector_type(8)));
typedef float f4v __attribute__((ext_vector_type(4)));

__device__ __forceinline__ ushort f2bf(float f) {      // RNE
    uint u = __float_as_uint(f);
    uint r = (u + 0x7FFFu + ((u >> 16) & 1u)) >> 16;
    return (ushort)r;
}
__device__ __forceinline__ ushort f2bf_t(float f) {    // truncate (hot paths)
    return (ushort)(__float_as_uint(f) >> 16);
}
__device__ __forceinline__ float bf2f(ushort s) {
    return __uint_as_float(((uint)s) << 16);
}
__device__ __forceinline__ float silu_f(float x) {
    return x * __fdividef(1.0f, 1.0f + __expf(-x));
}
__device__ __forceinline__ uint pack2bf_t(float lo, float hi) {
    return __builtin_amdgcn_perm(__float_as_uint(hi), __float_as_uint(lo), 0x07060302u);
}
__device__ __forceinline__ uint pack2bf_r(float lo, float hi) {
    uint a = __float_as_uint(lo) + 0x8000u;
    uint b = __float_as_uint(hi) + 0x8000u;
    return __builtin_amdgcn_perm(b, a, 0x07060302u);
}

// ---------------- merged weight pre-swizzle ----------------
// element = src[l*lstride + k*128 + n] (k<K else 0); dst [L,KC,t(8),lane(64),j(8)]
__device__ __forceinline__ void swz_one(const float* src, ushort* dst, int K, int lstride, int KC, int idx)
{
    int per = KC * 4096;
    int l = idx / per, r = idx % per;
    int fb = r >> 9, rem = r & 511;
    int lane = rem >> 3, jj = rem & 7;
    int kc = fb >> 3, t = fb & 7;
    int k = kc * 32 + ((lane >> 4) << 3) + jj;
    int n = t * 16 + (lane & 15);
    float v = (k < K) ? src[(size_t)l * lstride + (size_t)k * 128 + n] : 0.0f;
    dst[idx] = f2bf(v);
}
__global__ void __launch_bounds__(256) k_swz_all(
    const float* __restrict__ eW1, const float* __restrict__ eW2, const float* __restrict__ cW1,
    const float* __restrict__ nW1, const float* __restrict__ nW2,
    const float* __restrict__ inW, const float* __restrict__ outW,
    ushort* __restrict__ oT, ushort* __restrict__ oM,
    ushort* __restrict__ o2, ushort* __restrict__ o3,
    ushort* __restrict__ o4, ushort* __restrict__ o5,
    ushort* __restrict__ o6, ushort* __restrict__ o7)
{
    int gid = blockIdx.x * 256 + threadIdx.x;
    if (gid < 65536)       swz_one(eW1,         oT, 128, 33024, 4, gid);           // W1_top
    else if (gid < 131072) swz_one(eW1 + 16384, oM, 128, 33024, 4, gid - 65536);   // W1_mid
    else if (gid < 196608) swz_one(eW2, o2, 128, 16384, 4, gid - 131072);
    else if (gid < 262144) swz_one(cW1, o3, 128, 16384, 4, gid - 196608);
    else if (gid < 393216) swz_one(nW1, o4, 256, 32768, 8, gid - 262144);
    else if (gid < 458752) swz_one(nW2, o5, 128, 16384, 4, gid - 393216);
    else if (gid < 466944) swz_one(inW, o6, 64, 8192, 2, gid - 458752);
    else if (gid < 483328) swz_one(outW, o7, 128, 16384, 4, gid - 466944);
}

// ---------------- incoming-edge histogram ----------------
__global__ void __launch_bounds__(256) k_count(const int* __restrict__ eidx, int* __restrict__ ecnt)
{
    int e = blockIdx.x * 256 + threadIdx.x;
    atomicAdd(&ecnt[eidx[Ee + e]], 1);
}

// ---------------- multi-block exclusive scan (3 passes) ----------------
__global__ void __launch_bounds__(256) k_bsum(const int* __restrict__ ecnt, int* __restrict__ bsum)
{
    __shared__ int ws[4];
    int tid = threadIdx.x, lane = tid & 63, w = tid >> 6;
    int i = blockIdx.x * 256 + tid;
    int x = (i < Nn) ? ecnt[i] : 0;
    #pragma unroll
    for (int off = 1; off < 64; off <<= 1) x += __shfl_xor(x, off, 64);
    if (lane == 0) ws[w] = x;
    __syncthreads();
    if (tid == 0) bsum[blockIdx.x] = ws[0] + ws[1] + ws[2] + ws[3];
}
__global__ void __launch_bounds__(256) k_bscan(int* __restrict__ bsum)
{
    __shared__ int ws[4];
    int tid = threadIdx.x, lane = tid & 63, w = tid >> 6;
    int x = (tid < NB_SCAN) ? bsum[tid] : 0;
    int s = x;
    #pragma unroll
    for (int off = 1; off < 64; off <<= 1) {
        int t = __shfl_up(s, off, 64);
        if (lane >= off) s += t;
    }
    if (lane == 63) ws[w] = s;
    __syncthreads();
    if (tid == 0) { int a = 0; for (int k = 0; k < 4; k++) { int t = ws[k]; ws[k] = a; a += t; } }
    __syncthreads();
    int excl = ws[w] + s - x;
    if (tid < NB_SCAN) bsum[tid] = excl;
}
__global__ void __launch_bounds__(256) k_cursor(const int* __restrict__ ecnt,
                                               const int* __restrict__ boff, int* __restrict__ cursor)
{
    __shared__ int ws[4];
    int tid = threadIdx.x, lane = tid & 63, w = tid >> 6;
    int i = blockIdx.x * 256 + tid;
    int x = (i < Nn) ? ecnt[i] : 0;
    int s = x;
    #pragma unroll
    for (int off = 1; off < 64; off <<= 1) {
        int t = __shfl_up(s, off, 64);
        if (lane >= off) s += t;
    }
    if (lane == 63) ws[w] = s;
    __syncthreads();
    if (tid == 0) { int a = 0; for (int k = 0; k < 4; k++) { int t = ws[k]; ws[k] = a; a += t; } }
    __syncthreads();
    int excl = ws[w] + s - x + boff[blockIdx.x];
    if (i < Nn) cursor[i] = excl;
}

// ---------------- scatter edges into col-sorted arrays ----------------
__global__ void __launch_bounds__(256) k_scatter(
    const int* __restrict__ eidx, const float* __restrict__ edge_attr,
    int* __restrict__ cursor,
    int* __restrict__ srow, int* __restrict__ scol, float* __restrict__ sattr)
{
    int e = blockIdx.x * 256 + threadIdx.x;
    int r = eidx[e], c = eidx[Ee + e];
    int p = atomicAdd(&cursor[c], 1);
    srow[p] = r; scol[p] = c; sattr[p] = edge_attr[e];
}

// ---------------- input embedding (transposed MFMA, K=64) + coord copy ----------------
__global__ void __launch_bounds__(512, 2) k_emb(
    const float* __restrict__ h_in, const float* __restrict__ coords,
    const ushort* __restrict__ ws_, const float* __restrict__ b,
    float* __restrict__ hbuf, ushort* __restrict__ hbf, float* __restrict__ cbuf)
{
    __shared__ alignas(16) ushort s_h[64 * HIN_STR];
    const int tid = threadIdx.x;
    const int nb = blockIdx.x * 64;
    #pragma unroll
    for (int i = 0; i < 2; i++) {
        int idx = i * 512 + tid;
        int e = idx >> 4, ch = idx & 15;
        int node = nb + e;
        float4 f = make_float4(0.f, 0.f, 0.f, 0.f);
        if (node < Nn) f = *(const float4*)(h_in + (size_t)node * 64 + ch * 4);
        ushort4 u; u.x = f2bf(f.x); u.y = f2bf(f.y); u.z = f2bf(f.z); u.w = f2bf(f.w);
        *(ushort4*)(s_h + e * HIN_STR + ch * 4) = u;
    }
    if (tid < 192) {
        int n = nb + tid / 3, d = tid % 3;
        if (n < Nn) cbuf[n * 3 + d] = coords[n * 3 + d];
    }
    __syncthreads();
    const int lane = tid & 63, wave = tid >> 6;
    const int m = lane & 15, quad = lane >> 4;
    const int ws2 = wave >> 2, wt = wave & 3;
    const int rbase = ws2 * 32;
    f4v acc[2][2];
    #pragma unroll
    for (int nt = 0; nt < 2; nt++) { acc[nt][0] = (f4v){0,0,0,0}; acc[nt][1] = (f4v){0,0,0,0}; }
    const ushort* aBase = ws_ + wt * 1024 + lane * 8;
    #pragma unroll
    for (int kc = 0; kc < 2; kc++) {
        s8v a0 = *(const s8v*)(aBase + kc * 4096);
        s8v a1 = *(const s8v*)(aBase + kc * 4096 + 512);
        #pragma unroll
        for (int nt = 0; nt < 2; nt++) {
            s8v bf = *(const s8v*)(s_h + (rbase + nt * 16 + m) * HIN_STR + kc * 32 + quad * 8);
            acc[nt][0] = __builtin_amdgcn_mfma_f32_16x16x32_bf16(a0, bf, acc[nt][0], 0, 0, 0);
            acc[nt][1] = __builtin_amdgcn_mfma_f32_16x16x32_bf16(a1, bf, acc[nt][1], 0, 0, 0);
        }
    }
    #pragma unroll
    for (int nt = 0; nt < 2; nt++) {
        int node = nb + rbase + nt * 16 + m;
        if (node < Nn) {
            #pragma unroll
            for (int ct = 0; ct < 2; ct++) {
                int colb = (wt * 2 + ct) * 16 + quad * 4;
                float4 bb = *(const float4*)(b + colb);
                float v0 = acc[nt][ct][0] + bb.x;
                float v1 = acc[nt][ct][1] + bb.y;
                float v2 = acc[nt][ct][2] + bb.z;
                float v3 = acc[nt][ct][3] + bb.w;
                *(float4*)(hbuf + (size_t)node * 128 + colb) = make_float4(v0, v1, v2, v3);
                uint2 pk; pk.x = pack2bf_r(v0, v1); pk.y = pack2bf_r(v2, v3);
                *(uint2*)(hbf + (size_t)node * 128 + colb) = pk;
            }
        }
    }
}

// ---------------- per-layer U/V precompute: U = h@W1_top + b1, V = h@W1_mid ----------------
// uvb[n][0..127] = U (bf16 RNE), uvb[n][128..255] = V
__global__ void __launch_bounds__(512, 2) k_uv(
    const ushort* __restrict__ hbf,
    const ushort* __restrict__ topW, const ushort* __restrict__ midW,
    const float* __restrict__ b1, ushort* __restrict__ uvb)
{
    __shared__ alignas(16) ushort s_h[64 * EF_STR];
    const int tid = threadIdx.x;
    const int nb = blockIdx.x * 64;
    #pragma unroll
    for (int i = 0; i < 2; i++) {
        int idx = i * 512 + tid;
        int e = idx >> 4, ch = idx & 15;
        int node = nb + e;
        uint4 v = make_uint4(0, 0, 0, 0);
        if (node < Nn) v = *(const uint4*)(hbf + (size_t)node * 128 + ch * 8);
        *(uint4*)(s_h + e * EF_STR + ch * 8) = v;
    }
    __syncthreads();
    const int lane = tid & 63, wave = tid >> 6;
    const int m = lane & 15, quad = lane >> 4;
    const int ws2 = wave >> 2, wt = wave & 3;
    const int rbase = ws2 * 32;
    f4v au[2][2], av[2][2];
    #pragma unroll
    for (int ct = 0; ct < 2; ct++) {
        float4 bb = *(const float4*)(b1 + (wt * 2 + ct) * 16 + quad * 4);
        au[0][ct] = (f4v){bb.x, bb.y, bb.z, bb.w};
        au[1][ct] = au[0][ct];
        av[0][ct] = (f4v){0,0,0,0};
        av[1][ct] = (f4v){0,0,0,0};
    }
    const ushort* tBase = topW + wt * 1024 + (size_t)lane * 8;
    const ushort* mBase = midW + wt * 1024 + (size_t)lane * 8;
    #pragma unroll
    for (int kc = 0; kc < 4; kc++) {
        s8v t0 = *(const s8v*)(tBase + kc * 4096);
        s8v t1 = *(const s8v*)(tBase + kc * 4096 + 512);
        s8v m0 = *(const s8v*)(mBase + kc * 4096);
        s8v m1 = *(const s8v*)(mBase + kc * 4096 + 512);
        #pragma unroll
        for (int nt = 0; nt < 2; nt++) {
            s8v bf = *(const s8v*)(s_h + (rbase + nt * 16 + m) * EF_STR + kc * 32 + quad * 8);
            au[nt][0] = __builtin_amdgcn_mfma_f32_16x16x32_bf16(t0, bf, au[nt][0], 0, 0, 0);
            au[nt][1] = __builtin_amdgcn_mfma_f32_16x16x32_bf16(t1, bf, au[nt][1], 0, 0, 0);
            av[nt][0] = __builtin_amdgcn_mfma_f32_16x16x32_bf16(m0, bf, av[nt][0], 0, 0, 0);
            av[nt][1] = __builtin_amdgcn_mfma_f32_16x16x32_bf16(m1, bf, av[nt][1], 0, 0, 0);
        }
    }
    #pragma unroll
    for (int nt = 0; nt < 2; nt++) {
        int node = nb + rbase + nt * 16 + m;
        if (node < Nn) {
            #pragma unroll
            for (int ct = 0; ct < 2; ct++) {
                int colb = (wt * 2 + ct) * 16 + quad * 4;
                uint2 pu; pu.x = pack2bf_r(au[nt][ct][0], au[nt][ct][1]);
                          pu.y = pack2bf_r(au[nt][ct][2], au[nt][ct][3]);
                *(uint2*)(uvb + (size_t)node * 256 + colb) = pu;
                uint2 pv; pv.x = pack2bf_r(av[nt][ct][0], av[nt][ct][1]);
                          pv.y = pack2bf_r(av[nt][ct][2], av[nt][ct][3]);
                *(uint2*)(uvb + (size_t)node * 256 + 128 + colb) = pv;
            }
        }
    }
}

// ---------------- phase-1 helper: one bf16-pair of ef1 pre-activation ----------------
__device__ __forceinline__ uint uv_term(uint uw, uint vw, float dist, float attr,
                                        const float* wdp, const float* wap, int j)
{
    float2 w2d = *(const float2*)(wdp + 2 * j);
    float2 w2a = *(const float2*)(wap + 2 * j);
    float lo = __uint_as_float(uw << 16) + __uint_as_float(vw << 16)
             + dist * w2d.x + attr * w2a.x;
    float hi = __uint_as_float(uw & 0xFFFF0000u) + __uint_as_float(vw & 0xFFFF0000u)
             + dist * w2d.y + attr * w2a.y;
    return pack2bf_t(silu_f(lo), silu_f(hi));
}

// ---------------- fused edge kernel: 128-edge tile, R1 barrier semantics ----------------
// Same per-edge access pattern and sequential block->edge mapping as the proven
// 64-tile kernel; tile doubled to amortize barrier drains / fixed overheads.
// s_a is REUSED for ef1 then efb (extra cheap barrier) so LDS = 39424 B
// -> 4 blocks/CU, 32 waves (full cap). Agg segments 32 edges -> ~half the
// boundary atomics per edge.
__global__ void __launch_bounds__(512, 8) k_edge(
    const float* __restrict__ cbuf,
    const int* __restrict__ srow, const int* __restrict__ scol, const float* __restrict__ sattr,
    const ushort* __restrict__ uvb,
    const float* __restrict__ wd, const float* __restrict__ wa,
    const ushort* __restrict__ w2s, const float* __restrict__ b2,
    const ushort* __restrict__ cw1s, const float* __restrict__ cb1,
    const float* __restrict__ cwc,
    float* __restrict__ agg_feat, float* __restrict__ agg_coord)
{
    __shared__ alignas(16) ushort s_a[128 * EF_STR];  // ef1, then efb (reused)
    __shared__ alignas(16) float  s_p[128 * 4];       // coord partials (4 wt slots)
    __shared__ float s_dist[128];
    __shared__ int   s_col[128];
    __shared__ float s_cd[128 * 3];

    const int tid = threadIdx.x;
    const int eb = blockIdx.x * 128;

    // phase 0: edge metadata (tid<128 only — keeps cbuf/idx load count per edge
    // identical to the proven 64-tile kernel)
    if (tid < 128) {
        int rw = srow[eb + tid], cl = scol[eb + tid];
        s_col[tid] = cl;
        float d0 = cbuf[rw * 3 + 0] - cbuf[cl * 3 + 0];
        float d1 = cbuf[rw * 3 + 1] - cbuf[cl * 3 + 1];
        float d2 = cbuf[rw * 3 + 2] - cbuf[cl * 3 + 2];
        s_cd[tid * 3 + 0] = d0; s_cd[tid * 3 + 1] = d1; s_cd[tid * 3 + 2] = d2;
        s_dist[tid] = d0 * d0 + d1 * d1 + d2 * d2;
    }
    __syncthreads(); // B0: metadata ready

    // phase 1: ef1 gather-add (4 threads/edge x 32 cols, two 16-col halves)
    {
        const int e = tid >> 2, ch = tid & 3;
        int row = srow[eb + e], col = scol[eb + e];
        float attr = sattr[eb + e];
        float dist = s_dist[e];
        const ushort* up = uvb + (size_t)col * 256 + ch * 32;
        const ushort* vp = uvb + (size_t)row * 256 + 128 + ch * 32;
        #pragma unroll
        for (int hf = 0; hf < 2; hf++) {
            uint4 ua = *(const uint4*)(up + hf * 16);
            uint4 ub = *(const uint4*)(up + hf * 16 + 8);
            uint4 va = *(const uint4*)(vp + hf * 16);
            uint4 vb = *(const uint4*)(vp + hf * 16 + 8);
            const float* wdp = wd + ch * 32 + hf * 16;
            const float* wap = wa + ch * 32 + hf * 16;
            uint4 q0, q1;
            q0.x = uv_term(ua.x, va.x, dist, attr, wdp, wap, 0);
            q0.y = uv_term(ua.y, va.y, dist, attr, wdp, wap, 1);
            q0.z = uv_term(ua.z, va.z, dist, attr, wdp, wap, 2);
            q0.w = uv_term(ua.w, va.w, dist, attr, wdp, wap, 3);
            *(uint4*)(s_a + e * EF_STR + ch * 32 + hf * 16) = q0;
            q1.x = uv_term(ub.x, vb.x, dist, attr, wdp, wap, 4);
            q1.y = uv_term(ub.y, vb.y, dist, attr, wdp, wap, 5);
            q1.z = uv_term(ub.z, vb.z, dist, attr, wdp, wap, 6);
            q1.w = uv_term(ub.w, vb.w, dist, attr, wdp, wap, 7);
            *(uint4*)(s_a + e * EF_STR + ch * 32 + hf * 16 + 8) = q1;
        }
    }
    __syncthreads(); // B1: ef1 ready

    const int lane = tid & 63, wave = tid >> 6;
    const int m = lane & 15, quad = lane >> 4;
    const int ws2 = wave >> 2, wt = wave & 3;
    const int rbase = ws2 * 64;

    // ---- GEMM2 (swapped operands): D[outch][edge], 4 mt row-tiles/wave ----
    f4v acc2[4][2];  // [mt][tt] — held across B2a
    {
        #pragma unroll
        for (int tt = 0; tt < 2; tt++) {
            float4 bb = *(const float4*)(b2 + (wt * 2 + tt) * 16 + quad * 4);
            f4v b4 = (f4v){bb.x, bb.y, bb.z, bb.w};
            #pragma unroll
            for (int mt = 0; mt < 4; mt++) acc2[mt][tt] = b4;
        }
        const ushort* bBase = w2s + wt * 1024 + (size_t)lane * 8;
        #pragma unroll
        for (int kc = 0; kc < 4; kc++) {
            s8v b0 = *(const s8v*)(bBase + kc * 4096);
            s8v b1v = *(const s8v*)(bBase + kc * 4096 + 512);
            #pragma unroll
            for (int mt = 0; mt < 4; mt++) {
                s8v a = *(const s8v*)(s_a + (rbase + mt * 16 + m) * EF_STR + kc * 32 + quad * 8);
                acc2[mt][0] = __builtin_amdgcn_mfma_f32_16x16x32_bf16(b0, a, acc2[mt][0], 0, 0, 0);
                acc2[mt][1] = __builtin_amdgcn_mfma_f32_16x16x32_bf16(b1v, a, acc2[mt][1], 0, 0, 0);
            }
        }
    }
    __syncthreads(); // B2a: all ef1 reads complete — s_a reusable
    #pragma unroll
    for (int mt = 0; mt < 4; mt++)
        #pragma unroll
        for (int tt = 0; tt < 2; tt++) {
            uint2 pk;
            pk.x = pack2bf_t(silu_f(acc2[mt][tt][0]), silu_f(acc2[mt][tt][1]));
            pk.y = pack2bf_t(silu_f(acc2[mt][tt][2]), silu_f(acc2[mt][tt][3]));
            *(uint2*)(s_a + (rbase + mt * 16 + m) * EF_STR + (wt * 2 + tt) * 16 + quad * 4) = pk;
        }
    __syncthreads(); // B2b: efb ready

    // ---- coord gate (swapped operands): in-lane weighted sum ----
    {
        f4v acc3[4][2];
        #pragma unroll
        for (int tt = 0; tt < 2; tt++) {
            float4 bb = *(const float4*)(cb1 + (wt * 2 + tt) * 16 + quad * 4);
            f4v b4 = (f4v){bb.x, bb.y, bb.z, bb.w};
            #pragma unroll
            for (int mt = 0; mt < 4; mt++) acc3[mt][tt] = b4;
        }
        const ushort* bBase = cw1s + wt * 1024 + (size_t)lane * 8;
        #pragma unroll
        for (int kc = 0; kc < 4; kc++) {
            s8v b0 = *(const s8v*)(bBase + kc * 4096);
            s8v b1v = *(const s8v*)(bBase + kc * 4096 + 512);
            #pragma unroll
            for (int mt = 0; mt < 4; mt++) {
                s8v a = *(const s8v*)(s_a + (rbase + mt * 16 + m) * EF_STR + kc * 32 + quad * 8);
                acc3[mt][0] = __builtin_amdgcn_mfma_f32_16x16x32_bf16(b0, a, acc3[mt][0], 0, 0, 0);
                acc3[mt][1] = __builtin_amdgcn_mfma_f32_16x16x32_bf16(b1v, a, acc3[mt][1], 0, 0, 0);
            }
        }
        float4 wc0 = *(const float4*)(cwc + (wt * 2 + 0) * 16 + quad * 4);
        float4 wc1 = *(const float4*)(cwc + (wt * 2 + 1) * 16 + quad * 4);
        #pragma unroll
        for (int mt = 0; mt < 4; mt++) {
            float p = silu_f(acc3[mt][0][0]) * wc0.x + silu_f(acc3[mt][0][1]) * wc0.y
                    + silu_f(acc3[mt][0][2]) * wc0.z + silu_f(acc3[mt][0][3]) * wc0.w
                    + silu_f(acc3[mt][1][0]) * wc1.x + silu_f(acc3[mt][1][1]) * wc1.y
                    + silu_f(acc3[mt][1][2]) * wc1.z + silu_f(acc3[mt][1][3]) * wc1.w;
            p += __shfl_xor(p, 16, 64);
            p += __shfl_xor(p, 32, 64);
            if (quad == 0) s_p[(rbase + mt * 16 + m) * 4 + wt] = p;
        }
    }
    __syncthreads(); // B3: partials ready

    if (tid < 128) {
        float4 pt = *(const float4*)(s_p + tid * 4);
        float cw = pt.x + pt.y + pt.z + pt.w;
        int cn = s_col[tid];
        unsafeAtomicAdd(&agg_coord[cn * 3 + 0], s_cd[tid * 3 + 0] * cw);
        unsafeAtomicAdd(&agg_coord[cn * 3 + 1], s_cd[tid * 3 + 1] * cw);
        unsafeAtomicAdd(&agg_coord[cn * 3 + 2], s_cd[tid * 3 + 2] * cw);
    }
    // feature aggregation: 4 segments x 32 edges, run-length reduced
    {
        int j = tid & 127;
        int e0 = (tid >> 7) * 32;
        float accv = 0.0f; int cur = s_col[e0];
        #pragma unroll 4
        for (int ee = e0; ee < e0 + 32; ee++) {
            int c = s_col[ee];
            if (c != cur) {
                unsafeAtomicAdd(&agg_feat[(size_t)cur * 128 + j], accv);
                accv = 0.0f; cur = c;
            }
            accv += bf2f(s_a[ee * EF_STR + j]);
        }
        unsafeAtomicAdd(&agg_feat[(size_t)cur * 128 + j], accv);
    }
}

// ---------------- node update (transposed MFMA) + agg re-zero for next layer ----------------
__global__ void __launch_bounds__(512, 6) k_node(
    float* __restrict__ hbuf, ushort* __restrict__ hbf, float* __restrict__ cbuf,
    float* __restrict__ agg_feat, float* __restrict__ agg_coord,
    const int* __restrict__ ecnt,
    const ushort* __restrict__ w1s, const float* __restrict__ b1,
    const ushort* __restrict__ w2s, const float* __restrict__ b2)
{
    __shared__ alignas(16) ushort s_nin[64 * NIN_STR];
    __shared__ alignas(16) ushort s_t1[64 * EF_STR];
    const int tid = threadIdx.x;
    const int nb = blockIdx.x * 64;

    #pragma unroll
    for (int i = 0; i < 2; i++) {
        int idx = i * 512 + tid;
        int e = idx >> 4, ch = idx & 15;
        int node = nb + e;
        uint4 v = make_uint4(0, 0, 0, 0);
        if (node < Nn) v = *(const uint4*)(hbf + (size_t)node * 128 + ch * 8);
        *(uint4*)(s_nin + e * NIN_STR + ch * 8) = v;
    }
    #pragma unroll
    for (int i = 0; i < 4; i++) {
        int idx = i * 512 + tid;
        int e = idx >> 5, ch = idx & 31;
        int node = nb + e;
        float4 f = make_float4(0.f, 0.f, 0.f, 0.f);
        if (node < Nn) {
            f = *(const float4*)(agg_feat + (size_t)node * 128 + ch * 4);
            *(float4*)(agg_feat + (size_t)node * 128 + ch * 4) = make_float4(0.f, 0.f, 0.f, 0.f);
        }
        uint2 pk; pk.x = pack2bf_t(f.x, f.y); pk.y = pack2bf_t(f.z, f.w);
        *(uint2*)(s_nin + e * NIN_STR + 128 + ch * 4) = pk;
    }
    if (tid < 64) {
        int n = nb + tid;
        if (n < Nn) {
            float c = (float)ecnt[n]; c = (c < 1.0f) ? 1.0f : c;
            float inv = __fdividef(1.0f, c);
            cbuf[n * 3 + 0] += agg_coord[n * 3 + 0] * inv;
            cbuf[n * 3 + 1] += agg_coord[n * 3 + 1] * inv;
            cbuf[n * 3 + 2] += agg_coord[n * 3 + 2] * inv;
            agg_coord[n * 3 + 0] = 0.f; agg_coord[n * 3 + 1] = 0.f; agg_coord[n * 3 + 2] = 0.f;
        }
    }
    __syncthreads();

    const int lane = tid & 63, wave = tid >> 6;
    const int m = lane & 15, quad = lane >> 4;
    const int ws2 = wave >> 2, wt = wave & 3;
    const int rbase = ws2 * 32;

    // GEMM1^T: K=256
    {
        f4v acc[2][2];
        #pragma unroll
        for (int ct = 0; ct < 2; ct++) {
            float4 bb = *(const float4*)(b1 + (wt * 2 + ct) * 16 + quad * 4);
            acc[0][ct] = (f4v){bb.x, bb.y, bb.z, bb.w};
            acc[1][ct] = acc[0][ct];
        }
        const ushort* aBase = w1s + wt * 1024 + (size_t)lane * 8;
        #pragma unroll
        for (int kc = 0; kc < 8; kc++) {
            s8v a0 = *(const s8v*)(aBase + kc * 4096);
            s8v a1 = *(const s8v*)(aBase + kc * 4096 + 512);
            #pragma unroll
            for (int nt = 0; nt < 2; nt++) {
                s8v bf = *(const s8v*)(s_nin + (rbase + nt * 16 + m) * NIN_STR + kc * 32 + quad * 8);
                acc[nt][0] = __builtin_amdgcn_mfma_f32_16x16x32_bf16(a0, bf, acc[nt][0], 0, 0, 0);
                acc[nt][1] = __builtin_amdgcn_mfma_f32_16x16x32_bf16(a1, bf, acc[nt][1], 0, 0, 0);
            }
        }
        #pragma unroll
        for (int nt = 0; nt < 2; nt++) {
            int row = rbase + nt * 16 + m;
            #pragma unroll
            for (int ct = 0; ct < 2; ct++) {
                int colb = (wt * 2 + ct) * 16 + quad * 4;
                float v0 = silu_f(acc[nt][ct][0]);
                float v1 = silu_f(acc[nt][ct][1]);
                float v2 = silu_f(acc[nt][ct][2]);
                float v3 = silu_f(acc[nt][ct][3]);
                uint2 pk; pk.x = pack2bf_t(v0, v1); pk.y = pack2bf_t(v2, v3);
                *(uint2*)(s_t1 + row * EF_STR + colb) = pk;
            }
        }
    }
    __syncthreads();

    // GEMM2^T: K=128, residual epilogue
    {
        f4v acc[2][2];
        #pragma unroll
        for (int ct = 0; ct < 2; ct++) {
            float4 bb = *(const float4*)(b2 + (wt * 2 + ct) * 16 + quad * 4);
            acc[0][ct] = (f4v){bb.x, bb.y, bb.z, bb.w};
            acc[1][ct] = acc[0][ct];
        }
        const ushort* aBase = w2s + wt * 1024 + (size_t)lane * 8;
        #pragma unroll
        for (int kc = 0; kc < 4; kc++) {
            s8v a0 = *(const s8v*)(aBase + kc * 4096);
            s8v a1 = *(const s8v*)(aBase + kc * 4096 + 512);
            #pragma unroll
            for (int nt = 0; nt < 2; nt++) {
                s8v bf = *(const s8v*)(s_t1 + (rbase + nt * 16 + m) * EF_STR + kc * 32 + quad * 8);
                acc[nt][0] = __builtin_amdgcn_mfma_f32_16x16x32_bf16(a0, bf, acc[nt][0], 0, 0, 0);
                acc[nt][1] = __builtin_amdgcn_mfma_f32_16x16x32_bf16(a1, bf, acc[nt][1], 0, 0, 0);
            }
        }
        #pragma unroll
        for (int nt = 0; nt < 2; nt++) {
            int node = nb + rbase + nt * 16 + m;
            if (node < Nn) {
                #pragma unroll
                for (int ct = 0; ct < 2; ct++) {
                    int colb = (wt * 2 + ct) * 16 + quad * 4;
                    float4 old = *(const float4*)(hbuf + (size_t)node * 128 + colb);
                    float v0 = old.x + acc[nt][ct][0];
                    float v1 = old.y + acc[nt][ct][1];
                    float v2 = old.z + acc[nt][ct][2];
                    float v3 = old.w + acc[nt][ct][3];
                    *(float4*)(hbuf + (size_t)node * 128 + colb) = make_float4(v0, v1, v2, v3);
                    uint2 pk; pk.x = pack2bf_r(v0, v1); pk.y = pack2bf_r(v2, v3);
                    *(uint2*)(hbf + (size_t)node * 128 + colb) = pk;
                }
            }
        }
    }
}

// ---------------- output embedding (transposed MFMA) + coords out ----------------
__global__ void __launch_bounds__(512, 2) k_emb_out(
    const ushort* __restrict__ hbf, const float* __restrict__ cbuf,
    const ushort* __restrict__ ws_, const float* __restrict__ b, float* __restrict__ out)
{
    __shared__ alignas(16) ushort s_h[64 * EF_STR];
    const int tid = threadIdx.x;
    const int nb = blockIdx.x * 64;
    #pragma unroll
    for (int i = 0; i < 2; i++) {
        int idx = i * 512 + tid;
        int e = idx >> 4, ch = idx & 15;
        int node = nb + e;
        uint4 v = make_uint4(0, 0, 0, 0);
        if (node < Nn) v = *(const uint4*)(hbf + (size_t)node * 128 + ch * 8);
        *(uint4*)(s_h + e * EF_STR + ch * 8) = v;
    }
    if (tid < 192) {
        int n = nb + tid / 3, d = tid % 3;
        if (n < Nn) out[(size_t)Nn * 128 + n * 3 + d] = cbuf[n * 3 + d];
    }
    __syncthreads();
    const int lane = tid & 63, wave = tid >> 6;
    const int m = lane & 15, quad = lane >> 4;
    const int ws2 = wave >> 2, wt = wave & 3;
    const int rbase = ws2 * 32;
    f4v acc[2][2];
    #pragma unroll
    for (int ct = 0; ct < 2; ct++) {
        float4 bb = *(const float4*)(b + (wt * 2 + ct) * 16 + quad * 4);
        acc[0][ct] = (f4v){bb.x, bb.y, bb.z, bb.w};
        acc[1][ct] = acc[0][ct];
    }
    const ushort* aBase = ws_ + wt * 1024 + (size_t)lane * 8;
    #pragma unroll
    for (int kc = 0; kc < 4; kc++) {
        s8v a0 = *(const s8v*)(aBase + kc * 4096);
        s8v a1 = *(const s8v*)(aBase + kc * 4096 + 512);
        #pragma unroll
        for (int nt = 0; nt < 2; nt++) {
            s8v bf = *(const s8v*)(s_h + (rbase + nt * 16 + m) * EF_STR + kc * 32 + quad * 8);
            acc[nt][0] = __builtin_amdgcn_mfma_f32_16x16x32_bf16(a0, bf, acc[nt][0], 0, 0, 0);
            acc[nt][1] = __builtin_amdgcn_mfma_f32_16x16x32_bf16(a1, bf, acc[nt][1], 0, 0, 0);
        }
    }
    #pragma unroll
    for (int nt = 0; nt < 2; nt++) {
        int node = nb + rbase + nt * 16 + m;
        if (node < Nn) {
            #pragma unroll
            for (int ct = 0; ct < 2; ct++) {
                int colb = (wt * 2 + ct) * 16 + quad * 4;
                float4 o = make_float4(acc[nt][ct][0], acc[nt][ct][1],
                                       acc[nt][ct][2], acc[nt][ct][3]);
                *(float4*)(out + (size_t)node * 128 + colb) = o;
            }
        }
    }
}

// ---------------- host launcher ----------------
extern "C" void kernel_launch(void* const* d_in, const int* in_sizes, int n_in,
                              void* d_out, int out_size, void* d_ws, size_t ws_size,
                              hipStream_t stream)
{
    const float* h_in      = (const float*)d_in[0];
    const float* coords    = (const float*)d_in[1];
    const float* edge_attr = (const float*)d_in[2];
    const float* emb_in_W  = (const float*)d_in[3];
    const float* emb_in_b  = (const float*)d_in[4];
    const float* emb_out_W = (const float*)d_in[5];
    const float* emb_out_b = (const float*)d_in[6];
    const float* eW1 = (const float*)d_in[7];
    const float* eb1 = (const float*)d_in[8];
    const float* eW2 = (const float*)d_in[9];
    const float* eb2 = (const float*)d_in[10];
    const float* cW1 = (const float*)d_in[11];
    const float* cb1 = (const float*)d_in[12];
    const float* cWc = (const float*)d_in[13];
    const float* nW1 = (const float*)d_in[14];
    const float* nb1 = (const float*)d_in[15];
    const float* nW2 = (const float*)d_in[16];
    const float* nb2 = (const float*)d_in[17];
    const int*  eidx = (const int*)d_in[18];

    size_t off = 0;
    char* base = (char*)d_ws;
    auto alloc = [&](size_t bytes) -> char* {
        char* p = base + off;
        off += (bytes + 255) & ~(size_t)255;
        return p;
    };
    float*  hbuf      = (float*)alloc((size_t)Nn * 128 * 4);
    ushort* hbf       = (ushort*)alloc((size_t)Nn * 128 * 2);
    ushort* uvb       = (ushort*)alloc((size_t)Nn * 256 * 2);
    float*  cbuf      = (float*)alloc((size_t)Nn * 3 * 4);
    int*    ecnt      = (int*)alloc((size_t)Nn * 4);
    int*    cursor    = (int*)alloc((size_t)Nn * 4);
    int*    bsum      = (int*)alloc((size_t)NB_SCAN * 4);
    int*    srow      = (int*)alloc((size_t)Ee * 4);
    int*    scol      = (int*)alloc((size_t)Ee * 4);
    float*  sattr     = (float*)alloc((size_t)Ee * 4);
    float*  agg_feat  = (float*)alloc((size_t)Nn * 128 * 4);
    float*  agg_coord = (float*)alloc((size_t)Nn * 3 * 4);
    ushort* eW1tops   = (ushort*)alloc((size_t)4 * 16384 * 2);
    ushort* eW1mids   = (ushort*)alloc((size_t)4 * 16384 * 2);
    ushort* eW2s      = (ushort*)alloc((size_t)4 * 16384 * 2);
    ushort* cW1s      = (ushort*)alloc((size_t)4 * 16384 * 2);
    ushort* nW1s      = (ushort*)alloc((size_t)4 * 32768 * 2);
    ushort* nW2s      = (ushort*)alloc((size_t)4 * 16384 * 2);
    ushort* eInWs     = (ushort*)alloc((size_t)8192 * 2);
    ushort* eOutWs    = (ushort*)alloc((size_t)16384 * 2);

    k_swz_all<<<483328 / 256, 256, 0, stream>>>(
        eW1, eW2, cW1, nW1, nW2, emb_in_W, emb_out_W,
        eW1tops, eW1mids, eW2s, cW1s, nW1s, nW2s, eInWs, eOutWs);

    hipMemsetAsync(ecnt, 0, (size_t)Nn * 4, stream);
    k_count<<<Ee / 256, 256, 0, stream>>>(eidx, ecnt);
    k_bsum<<<NB_SCAN, 256, 0, stream>>>(ecnt, bsum);
    k_bscan<<<1, 256, 0, stream>>>(bsum);
    k_cursor<<<NB_SCAN, 256, 0, stream>>>(ecnt, bsum, cursor);
    k_scatter<<<Ee / 256, 256, 0, stream>>>(eidx, edge_attr, cursor, srow, scol, sattr);
    k_emb<<<(Nn + 63) / 64, 512, 0, stream>>>(h_in, coords, eInWs, emb_in_b, hbuf, hbf, cbuf);

    hipMemsetAsync(agg_feat, 0, (size_t)Nn * 128 * 4, stream);
    hipMemsetAsync(agg_coord, 0, (size_t)Nn * 3 * 4, stream);

    for (int l = 0; l < 4; l++) {
        k_uv<<<(Nn + 63) / 64, 512, 0, stream>>>(
            hbf, eW1tops + (size_t)l * 16384, eW1mids + (size_t)l * 16384,
            eb1 + l * 128, uvb);
        k_edge<<<Ee / 128, 512, 0, stream>>>(
            cbuf, srow, scol, sattr, uvb,
            eW1 + ((size_t)l * 258 + 256) * 128,   // Wd = W1 row 256
            eW1 + ((size_t)l * 258 + 257) * 128,   // Wa = W1 row 257
            eW2s + (size_t)l * 16384, eb2 + l * 128,
            cW1s + (size_t)l * 16384, cb1 + l * 128,
            cWc + l * 128,
            agg_feat, agg_coord);
        k_node<<<(Nn + 63) / 64, 512, 0, stream>>>(
            hbuf, hbf, cbuf, agg_feat, agg_coord, ecnt,
            nW1s + (size_t)l * 32768, nb1 + l * 128,
            nW2s + (size_t)l * 16384, nb2 + l * 128);
    }
    k_emb_out<<<(Nn + 63) / 64, 512, 0, stream>>>(hbf, cbuf, eOutWs, emb_out_b, (float*)d_out);
}

// Round 5
// 1431.289 us; speedup vs baseline: 1.8348x; 1.1031x over previous
//
#include <hip/hip_runtime.h>

// ---------------- problem constants ----------------
constexpr int Nn = 50000;
constexpr int Ee = 800000;
constexpr int EF_STR  = 136; // 68 dw
constexpr int NIN_STR = 264; // 132 dw
constexpr int HIN_STR = 72;  // 36 dw
constexpr int NB_SCAN = (Nn + 255) / 256; // 196

typedef short s8v __attribute__((ext_vector_type(8)));
typedef float f4v __attribute__((ext_vector_type(4)));

__device__ __forceinline__ ushort f2bf(float f) {      // RNE
    uint u = __float_as_uint(f);
    uint r = (u + 0x7FFFu + ((u >> 16) & 1u)) >> 16;
    return (ushort)r;
}
__device__ __forceinline__ ushort f2bf_t(float f) {    // truncate (hot paths)
    return (ushort)(__float_as_uint(f) >> 16);
}
__device__ __forceinline__ float bf2f(ushort s) {
    return __uint_as_float(((uint)s) << 16);
}
__device__ __forceinline__ float silu_f(float x) {
    return x * __fdividef(1.0f, 1.0f + __expf(-x));
}
__device__ __forceinline__ uint pack2bf_t(float lo, float hi) {
    return __builtin_amdgcn_perm(__float_as_uint(hi), __float_as_uint(lo), 0x07060302u);
}
__device__ __forceinline__ uint pack2bf_r(float lo, float hi) {
    uint a = __float_as_uint(lo) + 0x8000u;
    uint b = __float_as_uint(hi) + 0x8000u;
    return __builtin_amdgcn_perm(b, a, 0x07060302u);
}

// ---------------- merged weight pre-swizzle ----------------
// element = src[l*lstride + k*128 + n] (k<K else 0); dst [L,KC,t(8),lane(64),j(8)]
__device__ __forceinline__ void swz_one(const float* src, ushort* dst, int K, int lstride, int KC, int idx)
{
    int per = KC * 4096;
    int l = idx / per, r = idx % per;
    int fb = r >> 9, rem = r & 511;
    int lane = rem >> 3, jj = rem & 7;
    int kc = fb >> 3, t = fb & 7;
    int k = kc * 32 + ((lane >> 4) << 3) + jj;
    int n = t * 16 + (lane & 15);
    float v = (k < K) ? src[(size_t)l * lstride + (size_t)k * 128 + n] : 0.0f;
    dst[idx] = f2bf(v);
}
__global__ void __launch_bounds__(256) k_swz_all(
    const float* __restrict__ eW1, const float* __restrict__ eW2, const float* __restrict__ cW1,
    const float* __restrict__ nW1, const float* __restrict__ nW2,
    const float* __restrict__ inW, const float* __restrict__ outW,
    ushort* __restrict__ oT, ushort* __restrict__ oM,
    ushort* __restrict__ o2, ushort* __restrict__ o3,
    ushort* __restrict__ o4, ushort* __restrict__ o5,
    ushort* __restrict__ o6, ushort* __restrict__ o7)
{
    int gid = blockIdx.x * 256 + threadIdx.x;
    if (gid < 65536)       swz_one(eW1,         oT, 128, 33024, 4, gid);           // W1_top
    else if (gid < 131072) swz_one(eW1 + 16384, oM, 128, 33024, 4, gid - 65536);   // W1_mid
    else if (gid < 196608) swz_one(eW2, o2, 128, 16384, 4, gid - 131072);
    else if (gid < 262144) swz_one(cW1, o3, 128, 16384, 4, gid - 196608);
    else if (gid < 393216) swz_one(nW1, o4, 256, 32768, 8, gid - 262144);
    else if (gid < 458752) swz_one(nW2, o5, 128, 16384, 4, gid - 393216);
    else if (gid < 466944) swz_one(inW, o6, 64, 8192, 2, gid - 458752);
    else if (gid < 483328) swz_one(outW, o7, 128, 16384, 4, gid - 466944);
}

// ---------------- incoming-edge histogram ----------------
__global__ void __launch_bounds__(256) k_count(const int* __restrict__ eidx, int* __restrict__ ecnt)
{
    int e = blockIdx.x * 256 + threadIdx.x;
    atomicAdd(&ecnt[eidx[Ee + e]], 1);
}

// ---------------- multi-block exclusive scan (3 passes) ----------------
__global__ void __launch_bounds__(256) k_bsum(const int* __restrict__ ecnt, int* __restrict__ bsum)
{
    __shared__ int ws[4];
    int tid = threadIdx.x, lane = tid & 63, w = tid >> 6;
    int i = blockIdx.x * 256 + tid;
    int x = (i < Nn) ? ecnt[i] : 0;
    #pragma unroll
    for (int off = 1; off < 64; off <<= 1) x += __shfl_xor(x, off, 64);
    if (lane == 0) ws[w] = x;
    __syncthreads();
    if (tid == 0) bsum[blockIdx.x] = ws[0] + ws[1] + ws[2] + ws[3];
}
__global__ void __launch_bounds__(256) k_bscan(int* __restrict__ bsum)
{
    __shared__ int ws[4];
    int tid = threadIdx.x, lane = tid & 63, w = tid >> 6;
    int x = (tid < NB_SCAN) ? bsum[tid] : 0;
    int s = x;
    #pragma unroll
    for (int off = 1; off < 64; off <<= 1) {
        int t = __shfl_up(s, off, 64);
        if (lane >= off) s += t;
    }
    if (lane == 63) ws[w] = s;
    __syncthreads();
    if (tid == 0) { int a = 0; for (int k = 0; k < 4; k++) { int t = ws[k]; ws[k] = a; a += t; } }
    __syncthreads();
    int excl = ws[w] + s - x;
    if (tid < NB_SCAN) bsum[tid] = excl;
}
__global__ void __launch_bounds__(256) k_cursor(const int* __restrict__ ecnt,
                                               const int* __restrict__ boff, int* __restrict__ cursor)
{
    __shared__ int ws[4];
    int tid = threadIdx.x, lane = tid & 63, w = tid >> 6;
    int i = blockIdx.x * 256 + tid;
    int x = (i < Nn) ? ecnt[i] : 0;
    int s = x;
    #pragma unroll
    for (int off = 1; off < 64; off <<= 1) {
        int t = __shfl_up(s, off, 64);
        if (lane >= off) s += t;
    }
    if (lane == 63) ws[w] = s;
    __syncthreads();
    if (tid == 0) { int a = 0; for (int k = 0; k < 4; k++) { int t = ws[k]; ws[k] = a; a += t; } }
    __syncthreads();
    int excl = ws[w] + s - x + boff[blockIdx.x];
    if (i < Nn) cursor[i] = excl;
}

// ---------------- scatter edges into col-sorted arrays ----------------
__global__ void __launch_bounds__(256) k_scatter(
    const int* __restrict__ eidx, const float* __restrict__ edge_attr,
    int* __restrict__ cursor,
    int* __restrict__ srow, int* __restrict__ scol, float* __restrict__ sattr)
{
    int e = blockIdx.x * 256 + threadIdx.x;
    int r = eidx[e], c = eidx[Ee + e];
    int p = atomicAdd(&cursor[c], 1);
    srow[p] = r; scol[p] = c; sattr[p] = edge_attr[e];
}

// ---------------- input embedding + fused layer-0 U/V ----------------
__global__ void __launch_bounds__(512, 2) k_emb(
    const float* __restrict__ h_in, const float* __restrict__ coords,
    const ushort* __restrict__ ws_, const float* __restrict__ b,
    float* __restrict__ hbuf, ushort* __restrict__ hbf, float* __restrict__ cbuf,
    const ushort* __restrict__ topW, const ushort* __restrict__ midW,
    const float* __restrict__ b1, ushort* __restrict__ uvb)
{
    __shared__ alignas(16) ushort s_h[64 * HIN_STR];
    __shared__ alignas(16) ushort s_hb[64 * EF_STR];   // h0 bf16 for the fused UV GEMM
    const int tid = threadIdx.x;
    const int nb = blockIdx.x * 64;
    #pragma unroll
    for (int i = 0; i < 2; i++) {
        int idx = i * 512 + tid;
        int e = idx >> 4, ch = idx & 15;
        int node = nb + e;
        float4 f = make_float4(0.f, 0.f, 0.f, 0.f);
        if (node < Nn) f = *(const float4*)(h_in + (size_t)node * 64 + ch * 4);
        ushort4 u; u.x = f2bf(f.x); u.y = f2bf(f.y); u.z = f2bf(f.z); u.w = f2bf(f.w);
        *(ushort4*)(s_h + e * HIN_STR + ch * 4) = u;
    }
    if (tid < 192) {
        int n = nb + tid / 3, d = tid % 3;
        if (n < Nn) cbuf[n * 3 + d] = coords[n * 3 + d];
    }
    __syncthreads();
    const int lane = tid & 63, wave = tid >> 6;
    const int m = lane & 15, quad = lane >> 4;
    const int ws2 = wave >> 2, wt = wave & 3;
    const int rbase = ws2 * 32;
    {
        f4v acc[2][2];
        #pragma unroll
        for (int nt = 0; nt < 2; nt++) { acc[nt][0] = (f4v){0,0,0,0}; acc[nt][1] = (f4v){0,0,0,0}; }
        const ushort* aBase = ws_ + wt * 1024 + lane * 8;
        #pragma unroll
        for (int kc = 0; kc < 2; kc++) {
            s8v a0 = *(const s8v*)(aBase + kc * 4096);
            s8v a1 = *(const s8v*)(aBase + kc * 4096 + 512);
            #pragma unroll
            for (int nt = 0; nt < 2; nt++) {
                s8v bf = *(const s8v*)(s_h + (rbase + nt * 16 + m) * HIN_STR + kc * 32 + quad * 8);
                acc[nt][0] = __builtin_amdgcn_mfma_f32_16x16x32_bf16(a0, bf, acc[nt][0], 0, 0, 0);
                acc[nt][1] = __builtin_amdgcn_mfma_f32_16x16x32_bf16(a1, bf, acc[nt][1], 0, 0, 0);
            }
        }
        #pragma unroll
        for (int nt = 0; nt < 2; nt++) {
            int node = nb + rbase + nt * 16 + m;
            #pragma unroll
            for (int ct = 0; ct < 2; ct++) {
                int colb = (wt * 2 + ct) * 16 + quad * 4;
                uint2 pk = make_uint2(0u, 0u);
                if (node < Nn) {
                    float4 bb = *(const float4*)(b + colb);
                    float v0 = acc[nt][ct][0] + bb.x;
                    float v1 = acc[nt][ct][1] + bb.y;
                    float v2 = acc[nt][ct][2] + bb.z;
                    float v3 = acc[nt][ct][3] + bb.w;
                    *(float4*)(hbuf + (size_t)node * 128 + colb) = make_float4(v0, v1, v2, v3);
                    pk.x = pack2bf_r(v0, v1); pk.y = pack2bf_r(v2, v3);
                    *(uint2*)(hbf + (size_t)node * 128 + colb) = pk;
                }
                *(uint2*)(s_hb + (rbase + nt * 16 + m) * EF_STR + colb) = pk;
            }
        }
    }
    __syncthreads(); // h0 ready in LDS — fused U/V GEMM (was k_uv)
    {
        f4v au[2][2], av[2][2];
        #pragma unroll
        for (int ct = 0; ct < 2; ct++) {
            float4 bb = *(const float4*)(b1 + (wt * 2 + ct) * 16 + quad * 4);
            au[0][ct] = (f4v){bb.x, bb.y, bb.z, bb.w};
            au[1][ct] = au[0][ct];
            av[0][ct] = (f4v){0,0,0,0};
            av[1][ct] = (f4v){0,0,0,0};
        }
        const ushort* tBase = topW + wt * 1024 + (size_t)lane * 8;
        const ushort* mBase = midW + wt * 1024 + (size_t)lane * 8;
        #pragma unroll
        for (int kc = 0; kc < 4; kc++) {
            s8v t0 = *(const s8v*)(tBase + kc * 4096);
            s8v t1 = *(const s8v*)(tBase + kc * 4096 + 512);
            s8v m0 = *(const s8v*)(mBase + kc * 4096);
            s8v m1 = *(const s8v*)(mBase + kc * 4096 + 512);
            #pragma unroll
            for (int nt = 0; nt < 2; nt++) {
                s8v bf = *(const s8v*)(s_hb + (rbase + nt * 16 + m) * EF_STR + kc * 32 + quad * 8);
                au[nt][0] = __builtin_amdgcn_mfma_f32_16x16x32_bf16(t0, bf, au[nt][0], 0, 0, 0);
                au[nt][1] = __builtin_amdgcn_mfma_f32_16x16x32_bf16(t1, bf, au[nt][1], 0, 0, 0);
                av[nt][0] = __builtin_amdgcn_mfma_f32_16x16x32_bf16(m0, bf, av[nt][0], 0, 0, 0);
                av[nt][1] = __builtin_amdgcn_mfma_f32_16x16x32_bf16(m1, bf, av[nt][1], 0, 0, 0);
            }
        }
        #pragma unroll
        for (int nt = 0; nt < 2; nt++) {
            int node = nb + rbase + nt * 16 + m;
            if (node < Nn) {
                #pragma unroll
                for (int ct = 0; ct < 2; ct++) {
                    int colb = (wt * 2 + ct) * 16 + quad * 4;
                    uint2 pu; pu.x = pack2bf_r(au[nt][ct][0], au[nt][ct][1]);
                              pu.y = pack2bf_r(au[nt][ct][2], au[nt][ct][3]);
                    *(uint2*)(uvb + (size_t)node * 256 + colb) = pu;
                    uint2 pv; pv.x = pack2bf_r(av[nt][ct][0], av[nt][ct][1]);
                              pv.y = pack2bf_r(av[nt][ct][2], av[nt][ct][3]);
                    *(uint2*)(uvb + (size_t)node * 256 + 128 + colb) = pv;
                }
            }
        }
    }
}

// ---------------- phase-1 helper: one bf16-pair of ef1 pre-activation ----------------
__device__ __forceinline__ uint uv_term(uint uw, uint vw, float dist, float attr,
                                        const float* wdp, const float* wap, int j)
{
    float2 w2d = *(const float2*)(wdp + 2 * j);
    float2 w2a = *(const float2*)(wap + 2 * j);
    float lo = __uint_as_float(uw << 16) + __uint_as_float(vw << 16)
             + dist * w2d.x + attr * w2a.x;
    float hi = __uint_as_float(uw & 0xFFFF0000u) + __uint_as_float(vw & 0xFFFF0000u)
             + dist * w2d.y + attr * w2a.y;
    return pack2bf_t(silu_f(lo), silu_f(hi));
}

// ---------------- fused edge kernel: 128-edge tile (R4 structure) ----------------
// + wd/wa staged in LDS (frees VMEM slots in phase 1); s_setprio around MFMA
// clusters (independent phase-diverse blocks -> scheduler can favor MFMA waves).
// LDS = 40448 B -> 4 blocks/CU.
__global__ void __launch_bounds__(512, 8) k_edge(
    const float* __restrict__ cbuf,
    const int* __restrict__ srow, const int* __restrict__ scol, const float* __restrict__ sattr,
    const ushort* __restrict__ uvb,
    const float* __restrict__ wd, const float* __restrict__ wa,
    const ushort* __restrict__ w2s, const float* __restrict__ b2,
    const ushort* __restrict__ cw1s, const float* __restrict__ cb1,
    const float* __restrict__ cwc,
    float* __restrict__ agg_feat, float* __restrict__ agg_coord)
{
    __shared__ alignas(16) ushort s_a[128 * EF_STR];  // ef1, then efb (reused)
    __shared__ alignas(16) float  s_p[128 * 4];       // coord partials (4 wt slots)
    __shared__ float s_dist[128];
    __shared__ int   s_col[128];
    __shared__ float s_cd[128 * 3];
    __shared__ alignas(16) float s_wd[128];
    __shared__ alignas(16) float s_wa[128];

    const int tid = threadIdx.x;
    const int eb = blockIdx.x * 128;

    // phase 0: edge metadata + weight-row staging
    if (tid < 128) {
        int rw = srow[eb + tid], cl = scol[eb + tid];
        s_col[tid] = cl;
        float d0 = cbuf[rw * 3 + 0] - cbuf[cl * 3 + 0];
        float d1 = cbuf[rw * 3 + 1] - cbuf[cl * 3 + 1];
        float d2 = cbuf[rw * 3 + 2] - cbuf[cl * 3 + 2];
        s_cd[tid * 3 + 0] = d0; s_cd[tid * 3 + 1] = d1; s_cd[tid * 3 + 2] = d2;
        s_dist[tid] = d0 * d0 + d1 * d1 + d2 * d2;
    } else if (tid < 256) {
        s_wd[tid - 128] = wd[tid - 128];
    } else if (tid < 384) {
        s_wa[tid - 256] = wa[tid - 256];
    }
    __syncthreads(); // B0: metadata + weights ready

    // phase 1: ef1 gather-add (4 threads/edge x 32 cols, two 16-col halves)
    {
        const int e = tid >> 2, ch = tid & 3;
        int row = srow[eb + e], col = scol[eb + e];
        float attr = sattr[eb + e];
        float dist = s_dist[e];
        const ushort* up = uvb + (size_t)col * 256 + ch * 32;
        const ushort* vp = uvb + (size_t)row * 256 + 128 + ch * 32;
        #pragma unroll
        for (int hf = 0; hf < 2; hf++) {
            uint4 ua = *(const uint4*)(up + hf * 16);
            uint4 ub = *(const uint4*)(up + hf * 16 + 8);
            uint4 va = *(const uint4*)(vp + hf * 16);
            uint4 vb = *(const uint4*)(vp + hf * 16 + 8);
            const float* wdp = s_wd + ch * 32 + hf * 16;
            const float* wap = s_wa + ch * 32 + hf * 16;
            uint4 q0, q1;
            q0.x = uv_term(ua.x, va.x, dist, attr, wdp, wap, 0);
            q0.y = uv_term(ua.y, va.y, dist, attr, wdp, wap, 1);
            q0.z = uv_term(ua.z, va.z, dist, attr, wdp, wap, 2);
            q0.w = uv_term(ua.w, va.w, dist, attr, wdp, wap, 3);
            *(uint4*)(s_a + e * EF_STR + ch * 32 + hf * 16) = q0;
            q1.x = uv_term(ub.x, vb.x, dist, attr, wdp, wap, 4);
            q1.y = uv_term(ub.y, vb.y, dist, attr, wdp, wap, 5);
            q1.z = uv_term(ub.z, vb.z, dist, attr, wdp, wap, 6);
            q1.w = uv_term(ub.w, vb.w, dist, attr, wdp, wap, 7);
            *(uint4*)(s_a + e * EF_STR + ch * 32 + hf * 16 + 8) = q1;
        }
    }
    __syncthreads(); // B1: ef1 ready

    const int lane = tid & 63, wave = tid >> 6;
    const int m = lane & 15, quad = lane >> 4;
    const int ws2 = wave >> 2, wt = wave & 3;
    const int rbase = ws2 * 64;

    // ---- GEMM2 (swapped operands): D[outch][edge], 4 mt row-tiles/wave ----
    f4v acc2[4][2];  // [mt][tt] — held across B2a
    {
        #pragma unroll
        for (int tt = 0; tt < 2; tt++) {
            float4 bb = *(const float4*)(b2 + (wt * 2 + tt) * 16 + quad * 4);
            f4v b4 = (f4v){bb.x, bb.y, bb.z, bb.w};
            #pragma unroll
            for (int mt = 0; mt < 4; mt++) acc2[mt][tt] = b4;
        }
        const ushort* bBase = w2s + wt * 1024 + (size_t)lane * 8;
        __builtin_amdgcn_s_setprio(1);
        #pragma unroll
        for (int kc = 0; kc < 4; kc++) {
            s8v b0 = *(const s8v*)(bBase + kc * 4096);
            s8v b1v = *(const s8v*)(bBase + kc * 4096 + 512);
            #pragma unroll
            for (int mt = 0; mt < 4; mt++) {
                s8v a = *(const s8v*)(s_a + (rbase + mt * 16 + m) * EF_STR + kc * 32 + quad * 8);
                acc2[mt][0] = __builtin_amdgcn_mfma_f32_16x16x32_bf16(b0, a, acc2[mt][0], 0, 0, 0);
                acc2[mt][1] = __builtin_amdgcn_mfma_f32_16x16x32_bf16(b1v, a, acc2[mt][1], 0, 0, 0);
            }
        }
        __builtin_amdgcn_s_setprio(0);
    }
    __syncthreads(); // B2a: all ef1 reads complete — s_a reusable
    #pragma unroll
    for (int mt = 0; mt < 4; mt++)
        #pragma unroll
        for (int tt = 0; tt < 2; tt++) {
            uint2 pk;
            pk.x = pack2bf_t(silu_f(acc2[mt][tt][0]), silu_f(acc2[mt][tt][1]));
            pk.y = pack2bf_t(silu_f(acc2[mt][tt][2]), silu_f(acc2[mt][tt][3]));
            *(uint2*)(s_a + (rbase + mt * 16 + m) * EF_STR + (wt * 2 + tt) * 16 + quad * 4) = pk;
        }
    __syncthreads(); // B2b: efb ready

    // ---- coord gate (swapped operands): in-lane weighted sum ----
    {
        f4v acc3[4][2];
        #pragma unroll
        for (int tt = 0; tt < 2; tt++) {
            float4 bb = *(const float4*)(cb1 + (wt * 2 + tt) * 16 + quad * 4);
            f4v b4 = (f4v){bb.x, bb.y, bb.z, bb.w};
            #pragma unroll
            for (int mt = 0; mt < 4; mt++) acc3[mt][tt] = b4;
        }
        const ushort* bBase = cw1s + wt * 1024 + (size_t)lane * 8;
        __builtin_amdgcn_s_setprio(1);
        #pragma unroll
        for (int kc = 0; kc < 4; kc++) {
            s8v b0 = *(const s8v*)(bBase + kc * 4096);
            s8v b1v = *(const s8v*)(bBase + kc * 4096 + 512);
            #pragma unroll
            for (int mt = 0; mt < 4; mt++) {
                s8v a = *(const s8v*)(s_a + (rbase + mt * 16 + m) * EF_STR + kc * 32 + quad * 8);
                acc3[mt][0] = __builtin_amdgcn_mfma_f32_16x16x32_bf16(b0, a, acc3[mt][0], 0, 0, 0);
                acc3[mt][1] = __builtin_amdgcn_mfma_f32_16x16x32_bf16(b1v, a, acc3[mt][1], 0, 0, 0);
            }
        }
        __builtin_amdgcn_s_setprio(0);
        float4 wc0 = *(const float4*)(cwc + (wt * 2 + 0) * 16 + quad * 4);
        float4 wc1 = *(const float4*)(cwc + (wt * 2 + 1) * 16 + quad * 4);
        #pragma unroll
        for (int mt = 0; mt < 4; mt++) {
            float p = silu_f(acc3[mt][0][0]) * wc0.x + silu_f(acc3[mt][0][1]) * wc0.y
                    + silu_f(acc3[mt][0][2]) * wc0.z + silu_f(acc3[mt][0][3]) * wc0.w
                    + silu_f(acc3[mt][1][0]) * wc1.x + silu_f(acc3[mt][1][1]) * wc1.y
                    + silu_f(acc3[mt][1][2]) * wc1.z + silu_f(acc3[mt][1][3]) * wc1.w;
            p += __shfl_xor(p, 16, 64);
            p += __shfl_xor(p, 32, 64);
            if (quad == 0) s_p[(rbase + mt * 16 + m) * 4 + wt] = p;
        }
    }
    __syncthreads(); // B3: partials ready

    if (tid < 128) {
        float4 pt = *(const float4*)(s_p + tid * 4);
        float cw = pt.x + pt.y + pt.z + pt.w;
        int cn = s_col[tid];
        unsafeAtomicAdd(&agg_coord[cn * 3 + 0], s_cd[tid * 3 + 0] * cw);
        unsafeAtomicAdd(&agg_coord[cn * 3 + 1], s_cd[tid * 3 + 1] * cw);
        unsafeAtomicAdd(&agg_coord[cn * 3 + 2], s_cd[tid * 3 + 2] * cw);
    }
    // feature aggregation: 4 segments x 32 edges, run-length reduced
    {
        int j = tid & 127;
        int e0 = (tid >> 7) * 32;
        float accv = 0.0f; int cur = s_col[e0];
        #pragma unroll 4
        for (int ee = e0; ee < e0 + 32; ee++) {
            int c = s_col[ee];
            if (c != cur) {
                unsafeAtomicAdd(&agg_feat[(size_t)cur * 128 + j], accv);
                accv = 0.0f; cur = c;
            }
            accv += bf2f(s_a[ee * EF_STR + j]);
        }
        unsafeAtomicAdd(&agg_feat[(size_t)cur * 128 + j], accv);
    }
}

// ---------------- node update + fused next-layer U/V ----------------
__global__ void __launch_bounds__(512, 6) k_node(
    float* __restrict__ hbuf, ushort* __restrict__ hbf, float* __restrict__ cbuf,
    float* __restrict__ agg_feat, float* __restrict__ agg_coord,
    const int* __restrict__ ecnt,
    const ushort* __restrict__ w1s, const float* __restrict__ b1,
    const ushort* __restrict__ w2s, const float* __restrict__ b2,
    const ushort* __restrict__ topW, const ushort* __restrict__ midW,
    const float* __restrict__ b1e, ushort* __restrict__ uvb, int do_uv)
{
    __shared__ alignas(16) ushort s_nin[64 * NIN_STR];
    __shared__ alignas(16) ushort s_t1[64 * EF_STR];
    const int tid = threadIdx.x;
    const int nb = blockIdx.x * 64;

    #pragma unroll
    for (int i = 0; i < 2; i++) {
        int idx = i * 512 + tid;
        int e = idx >> 4, ch = idx & 15;
        int node = nb + e;
        uint4 v = make_uint4(0, 0, 0, 0);
        if (node < Nn) v = *(const uint4*)(hbf + (size_t)node * 128 + ch * 8);
        *(uint4*)(s_nin + e * NIN_STR + ch * 8) = v;
    }
    #pragma unroll
    for (int i = 0; i < 4; i++) {
        int idx = i * 512 + tid;
        int e = idx >> 5, ch = idx & 31;
        int node = nb + e;
        float4 f = make_float4(0.f, 0.f, 0.f, 0.f);
        if (node < Nn) {
            f = *(const float4*)(agg_feat + (size_t)node * 128 + ch * 4);
            *(float4*)(agg_feat + (size_t)node * 128 + ch * 4) = make_float4(0.f, 0.f, 0.f, 0.f);
        }
        uint2 pk; pk.x = pack2bf_t(f.x, f.y); pk.y = pack2bf_t(f.z, f.w);
        *(uint2*)(s_nin + e * NIN_STR + 128 + ch * 4) = pk;
    }
    if (tid < 64) {
        int n = nb + tid;
        if (n < Nn) {
            float c = (float)ecnt[n]; c = (c < 1.0f) ? 1.0f : c;
            float inv = __fdividef(1.0f, c);
            cbuf[n * 3 + 0] += agg_coord[n * 3 + 0] * inv;
            cbuf[n * 3 + 1] += agg_coord[n * 3 + 1] * inv;
            cbuf[n * 3 + 2] += agg_coord[n * 3 + 2] * inv;
            agg_coord[n * 3 + 0] = 0.f; agg_coord[n * 3 + 1] = 0.f; agg_coord[n * 3 + 2] = 0.f;
        }
    }
    __syncthreads();

    const int lane = tid & 63, wave = tid >> 6;
    const int m = lane & 15, quad = lane >> 4;
    const int ws2 = wave >> 2, wt = wave & 3;
    const int rbase = ws2 * 32;

    // GEMM1^T: K=256
    {
        f4v acc[2][2];
        #pragma unroll
        for (int ct = 0; ct < 2; ct++) {
            float4 bb = *(const float4*)(b1 + (wt * 2 + ct) * 16 + quad * 4);
            acc[0][ct] = (f4v){bb.x, bb.y, bb.z, bb.w};
            acc[1][ct] = acc[0][ct];
        }
        const ushort* aBase = w1s + wt * 1024 + (size_t)lane * 8;
        #pragma unroll
        for (int kc = 0; kc < 8; kc++) {
            s8v a0 = *(const s8v*)(aBase + kc * 4096);
            s8v a1 = *(const s8v*)(aBase + kc * 4096 + 512);
            #pragma unroll
            for (int nt = 0; nt < 2; nt++) {
                s8v bf = *(const s8v*)(s_nin + (rbase + nt * 16 + m) * NIN_STR + kc * 32 + quad * 8);
                acc[nt][0] = __builtin_amdgcn_mfma_f32_16x16x32_bf16(a0, bf, acc[nt][0], 0, 0, 0);
                acc[nt][1] = __builtin_amdgcn_mfma_f32_16x16x32_bf16(a1, bf, acc[nt][1], 0, 0, 0);
            }
        }
        #pragma unroll
        for (int nt = 0; nt < 2; nt++) {
            int row = rbase + nt * 16 + m;
            #pragma unroll
            for (int ct = 0; ct < 2; ct++) {
                int colb = (wt * 2 + ct) * 16 + quad * 4;
                float v0 = silu_f(acc[nt][ct][0]);
                float v1 = silu_f(acc[nt][ct][1]);
                float v2 = silu_f(acc[nt][ct][2]);
                float v3 = silu_f(acc[nt][ct][3]);
                uint2 pk; pk.x = pack2bf_t(v0, v1); pk.y = pack2bf_t(v2, v3);
                *(uint2*)(s_t1 + row * EF_STR + colb) = pk;
            }
        }
    }
    __syncthreads();

    // GEMM2^T: K=128, residual epilogue; h_new bf16 also staged to s_nin for UV
    {
        f4v acc[2][2];
        #pragma unroll
        for (int ct = 0; ct < 2; ct++) {
            float4 bb = *(const float4*)(b2 + (wt * 2 + ct) * 16 + quad * 4);
            acc[0][ct] = (f4v){bb.x, bb.y, bb.z, bb.w};
            acc[1][ct] = acc[0][ct];
        }
        const ushort* aBase = w2s + wt * 1024 + (size_t)lane * 8;
        #pragma unroll
        for (int kc = 0; kc < 4; kc++) {
            s8v a0 = *(const s8v*)(aBase + kc * 4096);
            s8v a1 = *(const s8v*)(aBase + kc * 4096 + 512);
            #pragma unroll
            for (int nt = 0; nt < 2; nt++) {
                s8v bf = *(const s8v*)(s_t1 + (rbase + nt * 16 + m) * EF_STR + kc * 32 + quad * 8);
                acc[nt][0] = __builtin_amdgcn_mfma_f32_16x16x32_bf16(a0, bf, acc[nt][0], 0, 0, 0);
                acc[nt][1] = __builtin_amdgcn_mfma_f32_16x16x32_bf16(a1, bf, acc[nt][1], 0, 0, 0);
            }
        }
        #pragma unroll
        for (int nt = 0; nt < 2; nt++) {
            int node = nb + rbase + nt * 16 + m;
            #pragma unroll
            for (int ct = 0; ct < 2; ct++) {
                int colb = (wt * 2 + ct) * 16 + quad * 4;
                uint2 pk = make_uint2(0u, 0u);
                if (node < Nn) {
                    float4 old = *(const float4*)(hbuf + (size_t)node * 128 + colb);
                    float v0 = old.x + acc[nt][ct][0];
                    float v1 = old.y + acc[nt][ct][1];
                    float v2 = old.z + acc[nt][ct][2];
                    float v3 = old.w + acc[nt][ct][3];
                    *(float4*)(hbuf + (size_t)node * 128 + colb) = make_float4(v0, v1, v2, v3);
                    pk.x = pack2bf_r(v0, v1); pk.y = pack2bf_r(v2, v3);
                    *(uint2*)(hbf + (size_t)node * 128 + colb) = pk;
                }
                if (do_uv)
                    *(uint2*)(s_nin + (rbase + nt * 16 + m) * EF_STR + colb) = pk;
            }
        }
    }

    // fused next-layer U/V (was k_uv) — h_new already staged in s_nin
    if (do_uv) {
        __syncthreads();
        f4v au[2][2], av[2][2];
        #pragma unroll
        for (int ct = 0; ct < 2; ct++) {
            float4 bb = *(const float4*)(b1e + (wt * 2 + ct) * 16 + quad * 4);
            au[0][ct] = (f4v){bb.x, bb.y, bb.z, bb.w};
            au[1][ct] = au[0][ct];
            av[0][ct] = (f4v){0,0,0,0};
            av[1][ct] = (f4v){0,0,0,0};
        }
        const ushort* tBase = topW + wt * 1024 + (size_t)lane * 8;
        const ushort* mBase = midW + wt * 1024 + (size_t)lane * 8;
        #pragma unroll
        for (int kc = 0; kc < 4; kc++) {
            s8v t0 = *(const s8v*)(tBase + kc * 4096);
            s8v t1 = *(const s8v*)(tBase + kc * 4096 + 512);
            s8v m0 = *(const s8v*)(mBase + kc * 4096);
            s8v m1 = *(const s8v*)(mBase + kc * 4096 + 512);
            #pragma unroll
            for (int nt = 0; nt < 2; nt++) {
                s8v bf = *(const s8v*)(s_nin + (rbase + nt * 16 + m) * EF_STR + kc * 32 + quad * 8);
                au[nt][0] = __builtin_amdgcn_mfma_f32_16x16x32_bf16(t0, bf, au[nt][0], 0, 0, 0);
                au[nt][1] = __builtin_amdgcn_mfma_f32_16x16x32_bf16(t1, bf, au[nt][1], 0, 0, 0);
                av[nt][0] = __builtin_amdgcn_mfma_f32_16x16x32_bf16(m0, bf, av[nt][0], 0, 0, 0);
                av[nt][1] = __builtin_amdgcn_mfma_f32_16x16x32_bf16(m1, bf, av[nt][1], 0, 0, 0);
            }
        }
        #pragma unroll
        for (int nt = 0; nt < 2; nt++) {
            int node = nb + rbase + nt * 16 + m;
            if (node < Nn) {
                #pragma unroll
                for (int ct = 0; ct < 2; ct++) {
                    int colb = (wt * 2 + ct) * 16 + quad * 4;
                    uint2 pu; pu.x = pack2bf_r(au[nt][ct][0], au[nt][ct][1]);
                              pu.y = pack2bf_r(au[nt][ct][2], au[nt][ct][3]);
                    *(uint2*)(uvb + (size_t)node * 256 + colb) = pu;
                    uint2 pv; pv.x = pack2bf_r(av[nt][ct][0], av[nt][ct][1]);
                              pv.y = pack2bf_r(av[nt][ct][2], av[nt][ct][3]);
                    *(uint2*)(uvb + (size_t)node * 256 + 128 + colb) = pv;
                }
            }
        }
    }
}

// ---------------- output embedding (transposed MFMA) + coords out ----------------
__global__ void __launch_bounds__(512, 2) k_emb_out(
    const ushort* __restrict__ hbf, const float* __restrict__ cbuf,
    const ushort* __restrict__ ws_, const float* __restrict__ b, float* __restrict__ out)
{
    __shared__ alignas(16) ushort s_h[64 * EF_STR];
    const int tid = threadIdx.x;
    const int nb = blockIdx.x * 64;
    #pragma unroll
    for (int i = 0; i < 2; i++) {
        int idx = i * 512 + tid;
        int e = idx >> 4, ch = idx & 15;
        int node = nb + e;
        uint4 v = make_uint4(0, 0, 0, 0);
        if (node < Nn) v = *(const uint4*)(hbf + (size_t)node * 128 + ch * 8);
        *(uint4*)(s_h + e * EF_STR + ch * 8) = v;
    }
    if (tid < 192) {
        int n = nb + tid / 3, d = tid % 3;
        if (n < Nn) out[(size_t)Nn * 128 + n * 3 + d] = cbuf[n * 3 + d];
    }
    __syncthreads();
    const int lane = tid & 63, wave = tid >> 6;
    const int m = lane & 15, quad = lane >> 4;
    const int ws2 = wave >> 2, wt = wave & 3;
    const int rbase = ws2 * 32;
    f4v acc[2][2];
    #pragma unroll
    for (int ct = 0; ct < 2; ct++) {
        float4 bb = *(const float4*)(b + (wt * 2 + ct) * 16 + quad * 4);
        acc[0][ct] = (f4v){bb.x, bb.y, bb.z, bb.w};
        acc[1][ct] = acc[0][ct];
    }
    const ushort* aBase = ws_ + wt * 1024 + (size_t)lane * 8;
    #pragma unroll
    for (int kc = 0; kc < 4; kc++) {
        s8v a0 = *(const s8v*)(aBase + kc * 4096);
        s8v a1 = *(const s8v*)(aBase + kc * 4096 + 512);
        #pragma unroll
        for (int nt = 0; nt < 2; nt++) {
            s8v bf = *(const s8v*)(s_h + (rbase + nt * 16 + m) * EF_STR + kc * 32 + quad * 8);
            acc[nt][0] = __builtin_amdgcn_mfma_f32_16x16x32_bf16(a0, bf, acc[nt][0], 0, 0, 0);
            acc[nt][1] = __builtin_amdgcn_mfma_f32_16x16x32_bf16(a1, bf, acc[nt][1], 0, 0, 0);
        }
    }
    #pragma unroll
    for (int nt = 0; nt < 2; nt++) {
        int node = nb + rbase + nt * 16 + m;
        if (node < Nn) {
            #pragma unroll
            for (int ct = 0; ct < 2; ct++) {
                int colb = (wt * 2 + ct) * 16 + quad * 4;
                float4 o = make_float4(acc[nt][ct][0], acc[nt][ct][1],
                                       acc[nt][ct][2], acc[nt][ct][3]);
                *(float4*)(out + (size_t)node * 128 + colb) = o;
            }
        }
    }
}

// ---------------- host launcher ----------------
extern "C" void kernel_launch(void* const* d_in, const int* in_sizes, int n_in,
                              void* d_out, int out_size, void* d_ws, size_t ws_size,
                              hipStream_t stream)
{
    const float* h_in      = (const float*)d_in[0];
    const float* coords    = (const float*)d_in[1];
    const float* edge_attr = (const float*)d_in[2];
    const float* emb_in_W  = (const float*)d_in[3];
    const float* emb_in_b  = (const float*)d_in[4];
    const float* emb_out_W = (const float*)d_in[5];
    const float* emb_out_b = (const float*)d_in[6];
    const float* eW1 = (const float*)d_in[7];
    const float* eb1 = (const float*)d_in[8];
    const float* eW2 = (const float*)d_in[9];
    const float* eb2 = (const float*)d_in[10];
    const float* cW1 = (const float*)d_in[11];
    const float* cb1 = (const float*)d_in[12];
    const float* cWc = (const float*)d_in[13];
    const float* nW1 = (const float*)d_in[14];
    const float* nb1 = (const float*)d_in[15];
    const float* nW2 = (const float*)d_in[16];
    const float* nb2 = (const float*)d_in[17];
    const int*  eidx = (const int*)d_in[18];

    size_t off = 0;
    char* base = (char*)d_ws;
    auto alloc = [&](size_t bytes) -> char* {
        char* p = base + off;
        off += (bytes + 255) & ~(size_t)255;
        return p;
    };
    float*  hbuf      = (float*)alloc((size_t)Nn * 128 * 4);
    ushort* hbf       = (ushort*)alloc((size_t)Nn * 128 * 2);
    ushort* uvb       = (ushort*)alloc((size_t)Nn * 256 * 2);
    float*  cbuf      = (float*)alloc((size_t)Nn * 3 * 4);
    int*    ecnt      = (int*)alloc((size_t)Nn * 4);
    int*    cursor    = (int*)alloc((size_t)Nn * 4);
    int*    bsum      = (int*)alloc((size_t)NB_SCAN * 4);
    int*    srow      = (int*)alloc((size_t)Ee * 4);
    int*    scol      = (int*)alloc((size_t)Ee * 4);
    float*  sattr     = (float*)alloc((size_t)Ee * 4);
    float*  agg_feat  = (float*)alloc((size_t)Nn * 128 * 4);
    float*  agg_coord = (float*)alloc((size_t)Nn * 3 * 4);
    ushort* eW1tops   = (ushort*)alloc((size_t)4 * 16384 * 2);
    ushort* eW1mids   = (ushort*)alloc((size_t)4 * 16384 * 2);
    ushort* eW2s      = (ushort*)alloc((size_t)4 * 16384 * 2);
    ushort* cW1s      = (ushort*)alloc((size_t)4 * 16384 * 2);
    ushort* nW1s      = (ushort*)alloc((size_t)4 * 32768 * 2);
    ushort* nW2s      = (ushort*)alloc((size_t)4 * 16384 * 2);
    ushort* eInWs     = (ushort*)alloc((size_t)8192 * 2);
    ushort* eOutWs    = (ushort*)alloc((size_t)16384 * 2);

    k_swz_all<<<483328 / 256, 256, 0, stream>>>(
        eW1, eW2, cW1, nW1, nW2, emb_in_W, emb_out_W,
        eW1tops, eW1mids, eW2s, cW1s, nW1s, nW2s, eInWs, eOutWs);

    hipMemsetAsync(ecnt, 0, (size_t)Nn * 4, stream);
    k_count<<<Ee / 256, 256, 0, stream>>>(eidx, ecnt);
    k_bsum<<<NB_SCAN, 256, 0, stream>>>(ecnt, bsum);
    k_bscan<<<1, 256, 0, stream>>>(bsum);
    k_cursor<<<NB_SCAN, 256, 0, stream>>>(ecnt, bsum, cursor);
    k_scatter<<<Ee / 256, 256, 0, stream>>>(eidx, edge_attr, cursor, srow, scol, sattr);
    k_emb<<<(Nn + 63) / 64, 512, 0, stream>>>(
        h_in, coords, eInWs, emb_in_b, hbuf, hbf, cbuf,
        eW1tops, eW1mids, eb1, uvb);   // fused layer-0 U/V

    hipMemsetAsync(agg_feat, 0, (size_t)Nn * 128 * 4, stream);
    hipMemsetAsync(agg_coord, 0, (size_t)Nn * 3 * 4, stream);

    for (int l = 0; l < 4; l++) {
        k_edge<<<Ee / 128, 512, 0, stream>>>(
            cbuf, srow, scol, sattr, uvb,
            eW1 + ((size_t)l * 258 + 256) * 128,   // Wd = W1 row 256
            eW1 + ((size_t)l * 258 + 257) * 128,   // Wa = W1 row 257
            eW2s + (size_t)l * 16384, eb2 + l * 128,
            cW1s + (size_t)l * 16384, cb1 + l * 128,
            cWc + l * 128,
            agg_feat, agg_coord);
        int ln = (l < 3) ? (l + 1) : 0;            // next-layer UV params (unused when do_uv=0)
        k_node<<<(Nn + 63) / 64, 512, 0, stream>>>(
            hbuf, hbf, cbuf, agg_feat, agg_coord, ecnt,
            nW1s + (size_t)l * 32768, nb1 + l * 128,
            nW2s + (size_t)l * 16384, nb2 + l * 128,
            eW1tops + (size_t)ln * 16384, eW1mids + (size_t)ln * 16384,
            eb1 + ln * 128, uvb, (l < 3) ? 1 : 0);
    }
    k_emb_out<<<(Nn + 63) / 64, 512, 0, stream>>>(hbf, cbuf, eOutWs, emb_out_b, (float*)d_out);
}